// Round 10
// baseline (759.197 us; speedup 1.0000x reference)
//
#include <hip/hip_runtime.h>
#include <stdint.h>

typedef unsigned long long u64;

__device__ __forceinline__ float sig_(float x) { return 1.0f / (1.0f + expf(-x)); }

#define NCAND 2535
#define NKEEP 300

// ---------------------------------------------------------------------------
// Pair-spatial 3x3 stride-2 conv body (2 horizontal outputs/thread), SAME
// padding (0 before / 1 after), OCT oc/thread, split-K. Triple-buffer
// rotation (no copy movs): window for ci+3 reloads the buffer just consumed,
// giving ~2 FMA-blocks of latency cover.
// ---------------------------------------------------------------------------
template <int CIN, int HIN, int WIN, int OCT, int SPLIT>
__device__ __forceinline__ void conv_p2_body(
    const float* __restrict__ in, const float* __restrict__ wgt,
    const float* __restrict__ bias, float* __restrict__ out) {
  constexpr int HOUT = HIN / 2, WOUT = WIN / 2, WP = WOUT / 2;
  constexpr int HWIN = HIN * WIN, HWOUT = HOUT * WOUT;
  constexpr int CS = CIN / SPLIT;
  static_assert(WOUT % 2 == 0 && WIN % 4 == 0, "pair layout");
  static_assert(CS >= 3, "triple buffer needs CS>=3");
  const int b = blockIdx.z / SPLIT, s = blockIdx.z % SPLIT;
  const int g = blockIdx.y;
  const int oc0 = g * OCT;
  const int COUT = gridDim.y * OCT;
  const int sp = blockIdx.x * 256 + threadIdx.x;
  if (sp >= HOUT * WP) return;
  const int oy = sp / WP, oxp = sp % WP;
  const int ox0 = oxp * 2;
  const int iy0 = oy * 2, ix0 = oxp * 4;
  const bool okY = (iy0 + 2 < HIN);
  const bool c4v = (ix0 + 4 < WIN);
  const float* inb =
      in + ((size_t)b * CIN + s * CS) * HWIN + (size_t)iy0 * WIN + ix0;
  const float* wbase = wgt + ((size_t)oc0 * CIN + s * CS) * 9;

  float acc0[OCT], acc1[OCT];
#pragma unroll
  for (int u = 0; u < OCT; u++) {
    acc0[u] = 0.0f;
    acc1[u] = 0.0f;
  }

  auto load15 = [&](float v[15], const float* ip) {
#pragma unroll
    for (int ky = 0; ky < 3; ky++) {
      const bool rok = (ky < 2) || okY;
      const float* rp = ip + ky * WIN;
      float4 p = make_float4(0.f, 0.f, 0.f, 0.f);
      float c4 = 0.f;
      if (rok) {
        p = *(const float4*)rp;  // 16B-aligned: ix0%4==0, WIN%4==0
        if (c4v) c4 = rp[4];
      }
      v[ky * 5 + 0] = p.x;
      v[ky * 5 + 1] = p.y;
      v[ky * 5 + 2] = p.z;
      v[ky * 5 + 3] = p.w;
      v[ky * 5 + 4] = c4;
    }
  };
  auto fmablk = [&](const float v[15], int ci) {
#pragma unroll
    for (int u = 0; u < OCT; u++) {
#pragma unroll
      for (int ky = 0; ky < 3; ky++) {
#pragma unroll
        for (int kx = 0; kx < 3; kx++) {
          const float w =
              wbase[(size_t)ci * 9 + (size_t)u * CIN * 9 + ky * 3 + kx];
          acc0[u] = fmaf(v[ky * 5 + kx], w, acc0[u]);
          acc1[u] = fmaf(v[ky * 5 + kx + 2], w, acc1[u]);
        }
      }
    }
  };

  float vA[15], vB[15], vC[15];
  load15(vA, inb);
  load15(vB, inb + HWIN);
  load15(vC, inb + 2 * (size_t)HWIN);
  for (int ci = 0; ci < CS; ci += 3) {
    fmablk(vA, ci);
    if (ci + 3 < CS) load15(vA, inb + (size_t)(ci + 3) * HWIN);
    if (ci + 1 < CS) {
      fmablk(vB, ci + 1);
      if (ci + 4 < CS) load15(vB, inb + (size_t)(ci + 4) * HWIN);
      if (ci + 2 < CS) {
        fmablk(vC, ci + 2);
        if (ci + 5 < CS) load15(vC, inb + (size_t)(ci + 5) * HWIN);
      }
    }
  }

  const size_t obase =
      (SPLIT == 1 ? (size_t)b * COUT : (size_t)(s * 8 + b) * COUT);
  float* ob = out + (obase + oc0) * HWOUT + (size_t)oy * WOUT + ox0;
  if (SPLIT == 1) {
#pragma unroll
    for (int u = 0; u < OCT; u++) {
      float r0 = acc0[u] + bias[oc0 + u];
      float r1 = acc1[u] + bias[oc0 + u];
      r0 = r0 > 0.0f ? r0 : 0.1f * r0;
      r1 = r1 > 0.0f ? r1 : 0.1f * r1;
      *(float2*)(ob + (size_t)u * HWOUT) = make_float2(r0, r1);
    }
  } else {
#pragma unroll
    for (int u = 0; u < OCT; u++)
      *(float2*)(ob + (size_t)u * HWOUT) = make_float2(acc0[u], acc1[u]);
  }
}

// Per-layer named wrappers (profile attribution). OCT=8 (round-8 proven).
__global__ __launch_bounds__(256) void k_conv1(const float* __restrict__ i,
                                               const float* __restrict__ w,
                                               const float* __restrict__ b,
                                               float* __restrict__ o) {
  conv_p2_body<3, 416, 416, 8, 1>(i, w, b, o);
}
__global__ __launch_bounds__(256) void k_conv2(const float* __restrict__ i,
                                               const float* __restrict__ w,
                                               const float* __restrict__ b,
                                               float* __restrict__ o) {
  conv_p2_body<32, 208, 208, 8, 1>(i, w, b, o);
}
__global__ __launch_bounds__(256) void k_conv3(const float* __restrict__ i,
                                               const float* __restrict__ w,
                                               const float* __restrict__ b,
                                               float* __restrict__ o) {
  conv_p2_body<64, 104, 104, 8, 2>(i, w, b, o);
}
__global__ __launch_bounds__(256) void k_conv4(const float* __restrict__ i,
                                               const float* __restrict__ w,
                                               const float* __restrict__ b,
                                               float* __restrict__ o) {
  conv_p2_body<128, 52, 52, 8, 4>(i, w, b, o);
}

// ---------------------------------------------------------------------------
// conv5: single-spatial (WOUT=13 odd), OCT=8, split-K x8, repacked weights
// [(g*8+s)][cl][u<8][k], triple-buffer rotation. Round-8 grid (1,64,64)x256.
// ---------------------------------------------------------------------------
__global__ __launch_bounds__(256) void k_conv5(const float* __restrict__ in,
                                               const float* __restrict__ wgt,
                                               float* __restrict__ out) {
  constexpr int CIN = 256, HIN = 26, WIN = 26, OCT = 8, SPLIT = 8;
  constexpr int HWIN = 676, HWOUT = 169, WOUT = 13;
  constexpr int CS = CIN / SPLIT;  // 32
  const int b = blockIdx.z / SPLIT, s = blockIdx.z % SPLIT;
  const int g = blockIdx.y;
  const int oc0 = g * OCT;
  constexpr int COUT = 512;
  const int sp = blockIdx.x * 256 + threadIdx.x;
  if (sp >= HWOUT) return;
  const int oy = sp / WOUT, ox = sp % WOUT;
  const int iy0 = oy * 2, ix0 = ox * 2;
  const bool okY = (iy0 + 2 < HIN);
  const bool okX = (ix0 + 2 < WIN);
  const float* inb =
      in + ((size_t)b * CIN + s * CS) * HWIN + (size_t)iy0 * WIN + ix0;
  const float* wbase = wgt + (size_t)(g * SPLIT + s) * CS * OCT * 9;

  float acc[OCT];
#pragma unroll
  for (int u = 0; u < OCT; u++) acc[u] = 0.0f;

  auto load9 = [&](float v[9], const float* ip) {
#pragma unroll
    for (int ky = 0; ky < 3; ky++) {
      const bool rok = (ky < 2) || okY;
      const float* rp = ip + ky * WIN;
      float a0 = 0.f, a1 = 0.f, a2 = 0.f;
      if (rok) {
        const float2 p = *(const float2*)rp;  // 8B-aligned
        a0 = p.x;
        a1 = p.y;
        if (okX) a2 = rp[2];
      }
      v[ky * 3 + 0] = a0;
      v[ky * 3 + 1] = a1;
      v[ky * 3 + 2] = a2;
    }
  };
  auto fmablk = [&](const float v[9], int ci) {
#pragma unroll
    for (int u = 0; u < OCT; u++) {
#pragma unroll
      for (int k = 0; k < 9; k++)
        acc[u] = fmaf(v[k], wbase[(size_t)ci * OCT * 9 + u * 9 + k], acc[u]);
    }
  };

  float vA[9], vB[9], vC[9];
  load9(vA, inb);
  load9(vB, inb + HWIN);
  load9(vC, inb + 2 * (size_t)HWIN);
  for (int ci = 0; ci < CS; ci += 3) {
    fmablk(vA, ci);
    if (ci + 3 < CS) load9(vA, inb + (size_t)(ci + 3) * HWIN);
    if (ci + 1 < CS) {
      fmablk(vB, ci + 1);
      if (ci + 4 < CS) load9(vB, inb + (size_t)(ci + 4) * HWIN);
      if (ci + 2 < CS) {
        fmablk(vC, ci + 2);
        if (ci + 5 < CS) load9(vC, inb + (size_t)(ci + 5) * HWIN);
      }
    }
  }

  float* ob = out + ((size_t)(s * 8 + b) * COUT + oc0) * HWOUT + sp;
#pragma unroll
  for (int u = 0; u < OCT; u++) ob[(size_t)u * HWOUT] = acc[u];
}

// ---------------------------------------------------------------------------
// 1x1 head body: OCT ch/thread, split-K, repacked weights, triple-buffer
// rotation over 4-channel chunks.
// ---------------------------------------------------------------------------
template <int CIN, int OCT, int SPLIT>
__device__ __forceinline__ void head_body(const float* __restrict__ in,
                                          const float* __restrict__ wgt,
                                          float* __restrict__ out, int HW) {
  constexpr int CS = CIN / SPLIT;  // 64 or 32
  static_assert(CS % 4 == 0 && CS >= 12, "chunking");
  const int sp = blockIdx.x * 256 + threadIdx.x;
  if (sp >= HW) return;
  const int g = blockIdx.y;
  const int oc0 = g * OCT;
  const int b = blockIdx.z / SPLIT, s = blockIdx.z % SPLIT;
  const float* ip = in + ((size_t)b * CIN + s * CS) * HW + sp;
  const float* wb = wgt + (size_t)(g * SPLIT + s) * CS * OCT;
  float acc[OCT];
#pragma unroll
  for (int u = 0; u < OCT; u++) acc[u] = 0.0f;

  auto ld4 = [&](float v[4], int base) {
#pragma unroll
    for (int j = 0; j < 4; j++) v[j] = ip[(size_t)(base + j) * HW];
  };
  auto fma4 = [&](const float v[4], int base) {
#pragma unroll
    for (int j = 0; j < 4; j++) {
#pragma unroll
      for (int u = 0; u < OCT; u++)
        acc[u] = fmaf(v[j], wb[(size_t)(base + j) * OCT + u], acc[u]);
    }
  };

  float vA[4], vB[4], vC[4];
  ld4(vA, 0);
  ld4(vB, 4);
  ld4(vC, 8);
  for (int c0 = 0; c0 < CS; c0 += 12) {
    fma4(vA, c0);
    if (c0 + 12 < CS) ld4(vA, c0 + 12);
    if (c0 + 4 < CS) {
      fma4(vB, c0 + 4);
      if (c0 + 16 < CS) ld4(vB, c0 + 16);
      if (c0 + 8 < CS) {
        fma4(vC, c0 + 8);
        if (c0 + 20 < CS) ld4(vC, c0 + 20);
      }
    }
  }
#pragma unroll
  for (int u = 0; u < OCT; u++)
    out[((size_t)(s * 8 + b) * 255 + oc0 + u) * HW + sp] = acc[u];
}

__global__ __launch_bounds__(256) void k_head2(const float* __restrict__ i,
                                               const float* __restrict__ w,
                                               float* __restrict__ o) {
  head_body<256, 17, 4>(i, w, o, 676);
}
__global__ __launch_bounds__(256) void k_head1(const float* __restrict__ i,
                                               const float* __restrict__ w,
                                               float* __restrict__ o) {
  head_body<512, 17, 16>(i, w, o, 169);
}

// ---------------------------------------------------------------------------
// Reduce SPLIT partials (slice-major, deterministic) + bias (+ lrelu).
// ---------------------------------------------------------------------------
template <int SPLIT, bool LRELU>
__global__ __launch_bounds__(256) void reduce_bias(
    const float* __restrict__ P, const float* __restrict__ bias,
    float* __restrict__ out, int COUT, int HWOUT, int N) {
  const int gid = blockIdx.x * 256 + threadIdx.x;
  if (gid >= N) return;
  float a = 0.0f;
#pragma unroll
  for (int s = 0; s < SPLIT; s++) a += P[(size_t)s * N + gid];
  const int oc = (gid / HWOUT) % COUT;
  a += bias[oc];
  if (LRELU) a = a > 0.0f ? a : 0.1f * a;
  out[gid] = a;
}

// ---------------------------------------------------------------------------
// Merged repack (round-8 layout): w5 (OCT=8, SPLIT=8), wh2 (OCT=17, SPLIT=4),
// wh1 (OCT=17, SPLIT=16).
// ---------------------------------------------------------------------------
__global__ __launch_bounds__(256) void k_repack(
    const float* __restrict__ w5, const float* __restrict__ wh2,
    const float* __restrict__ wh1, float* __restrict__ w5r,
    float* __restrict__ wh2r, float* __restrict__ wh1r) {
  const int gid = blockIdx.x * 256 + threadIdx.x;
  if (gid < 1179648) {  // w5: COUT=512, CIN=256, CS=32, OCT=8
    const int oc = gid / (256 * 9), r = gid % (256 * 9);
    const int ci = r / 9, k = r % 9;
    const int g = oc / 8, u = oc % 8, s = ci / 32, cl = ci % 32;
    w5r[(((size_t)(g * 8 + s) * 32 + cl) * 8 + u) * 9 + k] = w5[gid];
  } else if (gid < 1179648 + 65280) {  // wh2: 255x256, CS=64
    const int t = gid - 1179648;
    const int oc = t / 256, ci = t % 256;
    const int g = oc / 17, u = oc % 17, s = ci / 64, cl = ci % 64;
    wh2r[((size_t)(g * 4 + s) * 64 + cl) * 17 + u] = wh2[t];
  } else if (gid < 1179648 + 65280 + 130560) {  // wh1: 255x512, CS=32
    const int t = gid - 1179648 - 65280;
    const int oc = t / 512, ci = t % 512;
    const int g = oc / 17, u = oc % 17, s = ci / 32, cl = ci % 32;
    wh1r[((size_t)(g * 16 + s) * 32 + cl) * 17 + u] = wh1[t];
  }
}

// ---------------------------------------------------------------------------
// Decode both heads -> cand[b][i][8] = {y1,x1,y2,x2,obj,cc,label,score} and
// packed keys (score_bits<<32)|(0xFFFFFFFF-i) matching jax.lax.top_k order.
// ---------------------------------------------------------------------------
__global__ __launch_bounds__(256) void decode_kernel(
    const float* __restrict__ feat1, const float* __restrict__ feat2,
    float* __restrict__ cand, u64* __restrict__ keys) {
  const int gid = blockIdx.x * 256 + threadIdx.x;
  if (gid >= 8 * NCAND) return;
  const int b = gid / NCAND;
  const int i = gid % NCAND;
  const float* p;
  int rem, HW, W;
  float aw, ah;
  if (i < 507) {
    const int a = i / 169;
    rem = i % 169;
    HW = 169;
    W = 13;
    const float AW[3] = {81.f, 135.f, 344.f};
    const float AH[3] = {82.f, 169.f, 319.f};
    aw = AW[a];
    ah = AH[a];
    p = feat1 + ((size_t)b * 255 + a * 85) * 169 + rem;
  } else {
    const int j = i - 507;
    const int a = j / 676;
    rem = j % 676;
    HW = 676;
    W = 26;
    const float AW[3] = {10.f, 23.f, 37.f};
    const float AH[3] = {14.f, 27.f, 58.f};
    aw = AW[a];
    ah = AH[a];
    p = feat2 + ((size_t)b * 255 + a * 85) * 676 + rem;
  }
  const int gy = rem / W, gx = rem % W;
  const float invW = 1.0f / (float)W;
  float cx = (sig_(p[0]) + (float)gx) * invW;
  float cy = (sig_(p[(size_t)HW]) + (float)gy) * invW;
  float bw = expf(p[(size_t)2 * HW]) * aw / 416.0f;
  float bh = expf(p[(size_t)3 * HW]) * ah / 416.0f;
  float obj = sig_(p[(size_t)4 * HW]);
  float best = p[(size_t)5 * HW];
  int lab = 0;
  for (int c = 1; c < 80; ++c) {
    float v = p[(size_t)(5 + c) * HW];
    if (v > best) {
      best = v;
      lab = c;
    }
  }
  float cc = sig_(best);
  float score = obj * cc;
  if (score < 0.1f) score = 0.0f;
  float* o = cand + (size_t)gid * 8;
  o[0] = (cy - bh * 0.5f) * 416.0f;
  o[1] = (cx - bw * 0.5f) * 416.0f;
  o[2] = (cy + bh * 0.5f) * 416.0f;
  o[3] = (cx + bw * 0.5f) * 416.0f;
  o[4] = obj;
  o[5] = cc;
  o[6] = (float)lab;
  o[7] = score;
  keys[gid] = ((u64)__float_as_uint(score) << 32) |
              (u64)(0xFFFFFFFFu - (unsigned)i);
}

// ---------------------------------------------------------------------------
// Exact top-300 via rank (distinct keys -> bijection): sel[rank]=idx.
// ---------------------------------------------------------------------------
__global__ __launch_bounds__(256) void rank_select_kernel(
    const u64* __restrict__ keys, int* __restrict__ sel) {
  const int b = blockIdx.y;
  __shared__ u64 k[NCAND];
  const u64* kb = keys + (size_t)b * NCAND;
  for (int t = threadIdx.x; t < NCAND; t += 256) k[t] = kb[t];
  __syncthreads();
  const int idx = blockIdx.x * 256 + threadIdx.x;
  if (idx >= NCAND) return;
  const u64 me = k[idx];
  int rank = 0;
#pragma unroll 4
  for (int j = 0; j < NCAND; j++) rank += (k[j] > me) ? 1 : 0;
  if (rank < NKEEP) sel[b * NKEEP + rank] = idx;
}

// ---------------------------------------------------------------------------
// Per-image NMS (same semantics as reference fori_loop; see round-7 notes).
// ---------------------------------------------------------------------------
__global__ __launch_bounds__(256) void nms_kernel(
    const float* __restrict__ cand, const int* __restrict__ sel,
    float* __restrict__ out) {
  const int b = blockIdx.x;
  const int tid = threadIdx.x;
  const float* cb = cand + (size_t)b * NCAND * 8;

  __shared__ float4 bxv[NKEEP];
  __shared__ float2 oc2[NKEEP];
  __shared__ int lv[NKEEP];
  __shared__ u64 msk[NKEEP][6];
  __shared__ u64 validw[5];
  __shared__ u64 keepw[5];

  for (int t = tid; t < NKEEP; t += 256) {
    const int idx = sel[b * NKEEP + t];
    const float* c = cb + (size_t)idx * 8;
    const float4 c0 = *(const float4*)c;
    const float4 c1 = *(const float4*)(c + 4);
    bxv[t] = c0;
    oc2[t] = make_float2(c1.x, c1.y);
    lv[t] = (int)c1.z | ((c1.w > 0.0f) ? 0x10000 : 0);
  }
  __syncthreads();

  {
    const u64 m1 = __ballot((lv[tid] & 0x10000) != 0);
    if ((tid & 63) == 0) validw[tid >> 6] = m1;
    const u64 m2 = __ballot(tid < 44 && (lv[tid + 256] & 0x10000) != 0);
    if (tid == 0) validw[4] = m2;
  }

  for (int t = tid; t < NKEEP; t += 256) {
    u64 w[5] = {0, 0, 0, 0, 0};
    const int lvt = lv[t];
    if ((lvt & 0x10000) && t + 1 < NKEEP) {
      const float4 a = bxv[t];
      const float aarea = (a.z - a.x) * (a.w - a.y);
      int lv1 = lv[t + 1];
      float4 bb1 = bxv[t + 1];
      int j2 = (t + 2 < NKEEP) ? t + 2 : NKEEP - 1;
      int lv2 = (t + 2 < NKEEP) ? lv[j2] : -1;
      float4 bb2 = bxv[j2];
      for (int j = t + 1; j < NKEEP; ++j) {
        const int lvj = lv1;
        const float4 bbj = bb1;
        lv1 = lv2;
        bb1 = bb2;
        const int jn = (j + 2 < NKEEP) ? j + 2 : NKEEP - 1;
        lv2 = (j + 2 < NKEEP) ? lv[jn] : -1;
        bb2 = bxv[jn];
        if (lvj == lvt) {
          const float ty = fmaxf(a.x, bbj.x), tx = fmaxf(a.y, bbj.y);
          const float ey = fminf(a.z, bbj.z), ex = fminf(a.w, bbj.w);
          const float dy = fmaxf(ey - ty, 0.0f), dx = fmaxf(ex - tx, 0.0f);
          const float inter = dy * dx;
          const float barea = (bbj.z - bbj.x) * (bbj.w - bbj.y);
          const float iou = inter / (aarea + barea - inter + 1e-9f);
          if (iou > 0.5f) w[j >> 6] |= 1ull << (j & 63);
        }
      }
    }
#pragma unroll
    for (int q = 0; q < 5; q++) msk[t][q] = w[q];
  }
  __syncthreads();

  if (tid < 64) {
    const int L = tid;
    u64 slot[5][5];
#pragma unroll
    for (int q = 0; q < 5; q++) {
      const int row = q * 64 + L;
#pragma unroll
      for (int w = 0; w < 5; w++)
        slot[q][w] = (row < NKEEP) ? msk[row][w] : 0ull;
    }
    u64 kw[5];
#pragma unroll
    for (int w = 0; w < 5; w++) kw[w] = validw[w];
#pragma unroll
    for (int q = 0; q < 5; q++) {
      const int nb = (q == 4) ? (NKEEP - 256) : 64;
      for (int bit = 0; bit < nb; ++bit) {
        u64 r[5];
#pragma unroll
        for (int w = 0; w < 5; w++) r[w] = __shfl(slot[q][w], bit, 64);
        const u64 m = 0ull - ((kw[q] >> bit) & 1ull);
#pragma unroll
        for (int w = 0; w < 5; w++) kw[w] &= ~(r[w] & m);
      }
    }
    if (L == 0) {
#pragma unroll
      for (int w = 0; w < 5; w++) keepw[w] = kw[w];
    }
  }
  __syncthreads();

  float* ob = out + (size_t)b * NKEEP * 7;
  for (int t = tid; t < NKEEP; t += 256) {
    const bool k = (keepw[t >> 6] >> (t & 63)) & 1ull;
    float* r = ob + (size_t)t * 7;
    if (k) {
      const float4 a = bxv[t];
      const float2 o2 = oc2[t];
      r[0] = a.x;
      r[1] = a.y;
      r[2] = a.z;
      r[3] = a.w;
      r[4] = o2.x;
      r[5] = o2.y;
      r[6] = (float)(lv[t] & 0xFFFF);
    } else {
      r[0] = 0.0f; r[1] = 0.0f; r[2] = 0.0f; r[3] = 0.0f;
      r[4] = 0.0f; r[5] = 0.0f; r[6] = 0.0f;
    }
  }
}

// ---------------------------------------------------------------------------
// Workspace (float offsets) — round-8 layout (lifetime-checked):
//   x1  : [0, 11075584)          x2/P: [11075584, 16613376)
//   P3  : [5537792, 11075584)    x3 : [0, 2768896)
//   x4  : [2768896, 4153344)     f2 : [4153344, 5532384)
//   x5  : [5532384, 6224608)     f1 : [6224608, 6569368)
//   w5r : [6224608, 7404256)     wh2r: [7404256, 7469536)
//   wh1r: [7469536, 7600096)
//   cd  : [6569368, 6731608)  keys: [6731608, 6772168)  sel: [6772168, 6774568)
// Peak = 16613376 floats = 66.5 MB.
// ---------------------------------------------------------------------------
extern "C" void kernel_launch(void* const* d_in, const int* in_sizes, int n_in,
                              void* d_out, int out_size, void* d_ws,
                              size_t ws_size, hipStream_t stream) {
  const float* images = (const float*)d_in[0];
  const float* w1 = (const float*)d_in[1];
  const float* b1 = (const float*)d_in[2];
  const float* w2 = (const float*)d_in[3];
  const float* b2 = (const float*)d_in[4];
  const float* w3 = (const float*)d_in[5];
  const float* b3 = (const float*)d_in[6];
  const float* w4 = (const float*)d_in[7];
  const float* b4 = (const float*)d_in[8];
  const float* w5 = (const float*)d_in[9];
  const float* b5 = (const float*)d_in[10];
  const float* wh1 = (const float*)d_in[11];
  const float* bh1 = (const float*)d_in[12];
  const float* wh2 = (const float*)d_in[13];
  const float* bh2 = (const float*)d_in[14];
  float* ws = (float*)d_ws;

  float* x1 = ws + 0;
  float* x2 = ws + 11075584;
  float* P3 = ws + 5537792;
  float* x3 = ws + 0;
  float* x4 = ws + 2768896;
  float* f2 = ws + 4153344;
  float* x5 = ws + 5532384;
  float* f1 = ws + 6224608;
  float* cd = ws + 6569368;
  u64* keys = (u64*)(ws + 6731608);
  int* sel = (int*)(ws + 6772168);
  float* P = ws + 11075584;
  float* w5r = ws + 6224608;
  float* wh2r = ws + 7404256;
  float* wh1r = ws + 7469536;

  // conv1: 2720 blocks
  k_conv1<<<dim3(85, 4, 8), 256, 0, stream>>>(images, w1, b1, x1);
  // conv2: 1408 blocks
  k_conv2<<<dim3(22, 8, 8), 256, 0, stream>>>(x1, w2, b2, x2);
  // conv3: split-K x2 -> 1536 blocks
  k_conv3<<<dim3(6, 16, 16), 256, 0, stream>>>(x2, w3, nullptr, P3);
  reduce_bias<2, true><<<(2768896 + 255) / 256, 256, 0, stream>>>(P3, b3, x3, 128, 2704, 2768896);
  // repack w5/wh2/wh1 (P3 dead now)
  k_repack<<<(1375488 + 255) / 256, 256, 0, stream>>>(w5, wh2, wh1, w5r, wh2r, wh1r);
  // conv4: split-K x4 -> 2048 blocks
  k_conv4<<<dim3(2, 32, 32), 256, 0, stream>>>(x3, w4, nullptr, P);
  reduce_bias<4, true><<<(1384448 + 255) / 256, 256, 0, stream>>>(P, b4, x4, 256, 676, 1384448);
  // head2: split-K x4 -> 1440 blocks
  k_head2<<<dim3(3, 15, 32), 256, 0, stream>>>(x4, wh2r, P);
  reduce_bias<4, false><<<(1379040 + 255) / 256, 256, 0, stream>>>(P, bh2, f2, 255, 676, 1379040);
  // conv5: split-K x8 -> 4096 blocks
  k_conv5<<<dim3(1, 64, 64), 256, 0, stream>>>(x4, w5r, P);
  reduce_bias<8, true><<<(692224 + 255) / 256, 256, 0, stream>>>(P, b5, x5, 512, 169, 692224);
  // head1: split-K x16 -> 1920 blocks
  k_head1<<<dim3(1, 15, 128), 256, 0, stream>>>(x5, wh1r, P);
  reduce_bias<16, false><<<(344760 + 255) / 256, 256, 0, stream>>>(P, bh1, f1, 255, 169, 344760);

  decode_kernel<<<80, 256, 0, stream>>>(f1, f2, cd, keys);
  rank_select_kernel<<<dim3(10, 8), 256, 0, stream>>>(keys, sel);
  nms_kernel<<<8, 256, 0, stream>>>(cd, sel, (float*)d_out);
}

// Round 11
// 652.222 us; speedup vs baseline: 1.1640x; 1.1640x over previous
//
#include <hip/hip_runtime.h>
#include <stdint.h>

typedef unsigned long long u64;

__device__ __forceinline__ float sig_(float x) { return 1.0f / (1.0f + expf(-x)); }

#define NCAND 2535
#define NKEEP 300

// ---------------------------------------------------------------------------
// Pair-spatial 3x3 stride-2 conv body (2 horizontal outputs/thread), SAME
// padding (0 before / 1 after), OCT oc/thread, split-K, depth-2 register
// prefetch (round-8 proven form: unroll-2 with copies).
// ---------------------------------------------------------------------------
template <int CIN, int HIN, int WIN, int OCT, int SPLIT>
__device__ __forceinline__ void conv_p2_body(
    const float* __restrict__ in, const float* __restrict__ wgt,
    const float* __restrict__ bias, float* __restrict__ out) {
  constexpr int HOUT = HIN / 2, WOUT = WIN / 2, WP = WOUT / 2;
  constexpr int HWIN = HIN * WIN, HWOUT = HOUT * WOUT;
  constexpr int CS = CIN / SPLIT;
  static_assert(WOUT % 2 == 0 && WIN % 4 == 0, "pair layout");
  const int b = blockIdx.z / SPLIT, s = blockIdx.z % SPLIT;
  const int g = blockIdx.y;
  const int oc0 = g * OCT;
  const int COUT = gridDim.y * OCT;
  const int sp = blockIdx.x * 256 + threadIdx.x;
  if (sp >= HOUT * WP) return;
  const int oy = sp / WP, oxp = sp % WP;
  const int ox0 = oxp * 2;
  const int iy0 = oy * 2, ix0 = oxp * 4;
  const bool okY = (iy0 + 2 < HIN);
  const bool c4v = (ix0 + 4 < WIN);
  const float* inb =
      in + ((size_t)b * CIN + s * CS) * HWIN + (size_t)iy0 * WIN + ix0;
  const float* wbase = wgt + ((size_t)oc0 * CIN + s * CS) * 9;

  float acc0[OCT], acc1[OCT];
#pragma unroll
  for (int u = 0; u < OCT; u++) {
    acc0[u] = 0.0f;
    acc1[u] = 0.0f;
  }

  auto load15 = [&](float v[15], const float* ip) {
#pragma unroll
    for (int ky = 0; ky < 3; ky++) {
      const bool rok = (ky < 2) || okY;
      const float* rp = ip + ky * WIN;
      float4 p = make_float4(0.f, 0.f, 0.f, 0.f);
      float c4 = 0.f;
      if (rok) {
        p = *(const float4*)rp;  // 16B-aligned: ix0%4==0, WIN%4==0
        if (c4v) c4 = rp[4];
      }
      v[ky * 5 + 0] = p.x;
      v[ky * 5 + 1] = p.y;
      v[ky * 5 + 2] = p.z;
      v[ky * 5 + 3] = p.w;
      v[ky * 5 + 4] = c4;
    }
  };
  auto fmablk = [&](const float v[15], int ci) {
#pragma unroll
    for (int u = 0; u < OCT; u++) {
#pragma unroll
      for (int ky = 0; ky < 3; ky++) {
#pragma unroll
        for (int kx = 0; kx < 3; kx++) {
          const float w =
              wbase[(size_t)ci * 9 + (size_t)u * CIN * 9 + ky * 3 + kx];
          acc0[u] = fmaf(v[ky * 5 + kx], w, acc0[u]);
          acc1[u] = fmaf(v[ky * 5 + kx + 2], w, acc1[u]);
        }
      }
    }
  };

  float vA[15], vB[15];
  load15(vA, inb);
  if (CS > 1) load15(vB, inb + HWIN);
  for (int ci = 0; ci < CS; ci += 2) {
    float nA[15];
    if (ci + 2 < CS) load15(nA, inb + (size_t)(ci + 2) * HWIN);
    fmablk(vA, ci);
    float nB[15];
    if (ci + 3 < CS) load15(nB, inb + (size_t)(ci + 3) * HWIN);
    if (ci + 1 < CS) fmablk(vB, ci + 1);
    if (ci + 2 < CS) {
#pragma unroll
      for (int k = 0; k < 15; k++) vA[k] = nA[k];
    }
    if (ci + 3 < CS) {
#pragma unroll
      for (int k = 0; k < 15; k++) vB[k] = nB[k];
    }
  }

  const size_t obase =
      (SPLIT == 1 ? (size_t)b * COUT : (size_t)(s * 8 + b) * COUT);
  float* ob = out + (obase + oc0) * HWOUT + (size_t)oy * WOUT + ox0;
  if (SPLIT == 1) {
#pragma unroll
    for (int u = 0; u < OCT; u++) {
      float r0 = acc0[u] + bias[oc0 + u];
      float r1 = acc1[u] + bias[oc0 + u];
      r0 = r0 > 0.0f ? r0 : 0.1f * r0;
      r1 = r1 > 0.0f ? r1 : 0.1f * r1;
      *(float2*)(ob + (size_t)u * HWOUT) = make_float2(r0, r1);
    }
  } else {
#pragma unroll
    for (int u = 0; u < OCT; u++)
      *(float2*)(ob + (size_t)u * HWOUT) = make_float2(acc0[u], acc1[u]);
  }
}

// Per-layer named wrappers (profile attribution). OCT=8 (round-8 proven).
__global__ __launch_bounds__(256) void k_conv1(const float* __restrict__ i,
                                               const float* __restrict__ w,
                                               const float* __restrict__ b,
                                               float* __restrict__ o) {
  conv_p2_body<3, 416, 416, 8, 1>(i, w, b, o);
}
__global__ __launch_bounds__(256) void k_conv2(const float* __restrict__ i,
                                               const float* __restrict__ w,
                                               const float* __restrict__ b,
                                               float* __restrict__ o) {
  conv_p2_body<32, 208, 208, 8, 1>(i, w, b, o);
}
__global__ __launch_bounds__(256) void k_conv3(const float* __restrict__ i,
                                               const float* __restrict__ w,
                                               const float* __restrict__ b,
                                               float* __restrict__ o) {
  conv_p2_body<64, 104, 104, 8, 2>(i, w, b, o);
}
__global__ __launch_bounds__(256) void k_conv4(const float* __restrict__ i,
                                               const float* __restrict__ w,
                                               const float* __restrict__ b,
                                               float* __restrict__ o) {
  conv_p2_body<128, 52, 52, 8, 4>(i, w, b, o);
}

// ---------------------------------------------------------------------------
// conv5: single-spatial (WOUT=13 odd), OCT=8, split-K x8, round-8 grid
// (1,64,64)x256. SINGLE CHANGE vs round 8: the block's 2304-float repacked
// weight slice is staged into LDS once (coalesced, 9 loads/thread), and the
// FMA block reads weights via wave-uniform ds_read (broadcast). Removes the
// per-ci s_waitcnt lgkmcnt stall on s_load weight streams (theory: ~150 cyc
// per 144-cyc FMA block = the measured 48% idle).
// ---------------------------------------------------------------------------
__global__ __launch_bounds__(256) void k_conv5(const float* __restrict__ in,
                                               const float* __restrict__ wgt,
                                               float* __restrict__ out) {
  constexpr int CIN = 256, HIN = 26, WIN = 26, OCT = 8, SPLIT = 8;
  constexpr int HWIN = 676, HWOUT = 169, WOUT = 13;
  constexpr int CS = CIN / SPLIT;  // 32
  constexpr int WELE = CS * OCT * 9;  // 2304 floats = 9.2 KB
  __shared__ float wlds[WELE];

  const int b = blockIdx.z / SPLIT, s = blockIdx.z % SPLIT;
  const int g = blockIdx.y;
  const int oc0 = g * OCT;
  constexpr int COUT = 512;
  const float* wbase = wgt + (size_t)(g * SPLIT + s) * WELE;
  // All 256 threads stage (no early return before the barrier).
  for (int t = threadIdx.x; t < WELE; t += 256) wlds[t] = wbase[t];
  __syncthreads();

  const int sp = threadIdx.x;  // gridDim.x == 1
  if (sp >= HWOUT) return;
  const int oy = sp / WOUT, ox = sp % WOUT;
  const int iy0 = oy * 2, ix0 = ox * 2;
  const bool okY = (iy0 + 2 < HIN);
  const bool okX = (ix0 + 2 < WIN);
  const float* inb =
      in + ((size_t)b * CIN + s * CS) * HWIN + (size_t)iy0 * WIN + ix0;

  float acc[OCT];
#pragma unroll
  for (int u = 0; u < OCT; u++) acc[u] = 0.0f;

  auto load9 = [&](float v[9], const float* ip) {
#pragma unroll
    for (int ky = 0; ky < 3; ky++) {
      const bool rok = (ky < 2) || okY;
      const float* rp = ip + ky * WIN;
      float a0 = 0.f, a1 = 0.f, a2 = 0.f;
      if (rok) {
        const float2 p = *(const float2*)rp;  // 8B-aligned
        a0 = p.x;
        a1 = p.y;
        if (okX) a2 = rp[2];
      }
      v[ky * 3 + 0] = a0;
      v[ky * 3 + 1] = a1;
      v[ky * 3 + 2] = a2;
    }
  };
  auto fmablk = [&](const float v[9], int ci) {
#pragma unroll
    for (int u = 0; u < OCT; u++) {
#pragma unroll
      for (int k = 0; k < 9; k++)
        acc[u] = fmaf(v[k], wlds[ci * OCT * 9 + u * 9 + k], acc[u]);
    }
  };

  float vA[9], vB[9];
  load9(vA, inb);
  load9(vB, inb + HWIN);
  for (int ci = 0; ci < CS; ci += 2) {
    float nA[9];
    if (ci + 2 < CS) load9(nA, inb + (size_t)(ci + 2) * HWIN);
    fmablk(vA, ci);
    float nB[9];
    if (ci + 3 < CS) load9(nB, inb + (size_t)(ci + 3) * HWIN);
    fmablk(vB, ci + 1);
    if (ci + 2 < CS) {
#pragma unroll
      for (int k = 0; k < 9; k++) vA[k] = nA[k];
    }
    if (ci + 3 < CS) {
#pragma unroll
      for (int k = 0; k < 9; k++) vB[k] = nB[k];
    }
  }

  float* ob = out + ((size_t)(s * 8 + b) * COUT + oc0) * HWOUT + sp;
#pragma unroll
  for (int u = 0; u < OCT; u++) ob[(size_t)u * HWOUT] = acc[u];
}

// ---------------------------------------------------------------------------
// 1x1 head body: OCT ch/thread, split-K, repacked weights, depth-2 prefetch
// (round-8 proven form).
// ---------------------------------------------------------------------------
template <int CIN, int OCT, int SPLIT>
__device__ __forceinline__ void head_body(const float* __restrict__ in,
                                          const float* __restrict__ wgt,
                                          float* __restrict__ out, int HW) {
  constexpr int CS = CIN / SPLIT;  // multiple of 8
  const int sp = blockIdx.x * 256 + threadIdx.x;
  if (sp >= HW) return;
  const int g = blockIdx.y;
  const int oc0 = g * OCT;
  const int b = blockIdx.z / SPLIT, s = blockIdx.z % SPLIT;
  const float* ip = in + ((size_t)b * CIN + s * CS) * HW + sp;
  const float* wb = wgt + (size_t)(g * SPLIT + s) * CS * OCT;
  float acc[OCT];
#pragma unroll
  for (int u = 0; u < OCT; u++) acc[u] = 0.0f;

  auto fma4 = [&](const float v[4], int base) {
#pragma unroll
    for (int j = 0; j < 4; j++) {
#pragma unroll
      for (int u = 0; u < OCT; u++)
        acc[u] = fmaf(v[j], wb[(size_t)(base + j) * OCT + u], acc[u]);
    }
  };

  float vA[4], vB[4];
#pragma unroll
  for (int j = 0; j < 4; j++) {
    vA[j] = ip[(size_t)j * HW];
    vB[j] = ip[(size_t)(4 + j) * HW];
  }
  for (int c0 = 0; c0 < CS; c0 += 8) {
    float nA[4];
    if (c0 + 8 < CS) {
#pragma unroll
      for (int j = 0; j < 4; j++) nA[j] = ip[(size_t)(c0 + 8 + j) * HW];
    }
    fma4(vA, c0);
    float nB[4];
    if (c0 + 12 < CS) {
#pragma unroll
      for (int j = 0; j < 4; j++) nB[j] = ip[(size_t)(c0 + 12 + j) * HW];
    }
    fma4(vB, c0 + 4);
    if (c0 + 8 < CS) {
#pragma unroll
      for (int j = 0; j < 4; j++) vA[j] = nA[j];
    }
    if (c0 + 12 < CS) {
#pragma unroll
      for (int j = 0; j < 4; j++) vB[j] = nB[j];
    }
  }
#pragma unroll
  for (int u = 0; u < OCT; u++)
    out[((size_t)(s * 8 + b) * 255 + oc0 + u) * HW + sp] = acc[u];
}

__global__ __launch_bounds__(256) void k_head2(const float* __restrict__ i,
                                               const float* __restrict__ w,
                                               float* __restrict__ o) {
  head_body<256, 17, 4>(i, w, o, 676);
}
__global__ __launch_bounds__(256) void k_head1(const float* __restrict__ i,
                                               const float* __restrict__ w,
                                               float* __restrict__ o) {
  head_body<512, 17, 16>(i, w, o, 169);
}

// ---------------------------------------------------------------------------
// Reduce SPLIT partials (slice-major, deterministic) + bias (+ lrelu).
// ---------------------------------------------------------------------------
template <int SPLIT, bool LRELU>
__global__ __launch_bounds__(256) void reduce_bias(
    const float* __restrict__ P, const float* __restrict__ bias,
    float* __restrict__ out, int COUT, int HWOUT, int N) {
  const int gid = blockIdx.x * 256 + threadIdx.x;
  if (gid >= N) return;
  float a = 0.0f;
#pragma unroll
  for (int s = 0; s < SPLIT; s++) a += P[(size_t)s * N + gid];
  const int oc = (gid / HWOUT) % COUT;
  a += bias[oc];
  if (LRELU) a = a > 0.0f ? a : 0.1f * a;
  out[gid] = a;
}

// ---------------------------------------------------------------------------
// Merged repack (round-8 layout): w5 (OCT=8, SPLIT=8), wh2 (OCT=17, SPLIT=4),
// wh1 (OCT=17, SPLIT=16).
// ---------------------------------------------------------------------------
__global__ __launch_bounds__(256) void k_repack(
    const float* __restrict__ w5, const float* __restrict__ wh2,
    const float* __restrict__ wh1, float* __restrict__ w5r,
    float* __restrict__ wh2r, float* __restrict__ wh1r) {
  const int gid = blockIdx.x * 256 + threadIdx.x;
  if (gid < 1179648) {  // w5: COUT=512, CIN=256, CS=32, OCT=8
    const int oc = gid / (256 * 9), r = gid % (256 * 9);
    const int ci = r / 9, k = r % 9;
    const int g = oc / 8, u = oc % 8, s = ci / 32, cl = ci % 32;
    w5r[(((size_t)(g * 8 + s) * 32 + cl) * 8 + u) * 9 + k] = w5[gid];
  } else if (gid < 1179648 + 65280) {  // wh2: 255x256, CS=64
    const int t = gid - 1179648;
    const int oc = t / 256, ci = t % 256;
    const int g = oc / 17, u = oc % 17, s = ci / 64, cl = ci % 64;
    wh2r[((size_t)(g * 4 + s) * 64 + cl) * 17 + u] = wh2[t];
  } else if (gid < 1179648 + 65280 + 130560) {  // wh1: 255x512, CS=32
    const int t = gid - 1179648 - 65280;
    const int oc = t / 512, ci = t % 512;
    const int g = oc / 17, u = oc % 17, s = ci / 32, cl = ci % 32;
    wh1r[((size_t)(g * 16 + s) * 32 + cl) * 17 + u] = wh1[t];
  }
}

// ---------------------------------------------------------------------------
// Decode both heads -> cand[b][i][8] = {y1,x1,y2,x2,obj,cc,label,score} and
// packed keys (score_bits<<32)|(0xFFFFFFFF-i) matching jax.lax.top_k order.
// ---------------------------------------------------------------------------
__global__ __launch_bounds__(256) void decode_kernel(
    const float* __restrict__ feat1, const float* __restrict__ feat2,
    float* __restrict__ cand, u64* __restrict__ keys) {
  const int gid = blockIdx.x * 256 + threadIdx.x;
  if (gid >= 8 * NCAND) return;
  const int b = gid / NCAND;
  const int i = gid % NCAND;
  const float* p;
  int rem, HW, W;
  float aw, ah;
  if (i < 507) {
    const int a = i / 169;
    rem = i % 169;
    HW = 169;
    W = 13;
    const float AW[3] = {81.f, 135.f, 344.f};
    const float AH[3] = {82.f, 169.f, 319.f};
    aw = AW[a];
    ah = AH[a];
    p = feat1 + ((size_t)b * 255 + a * 85) * 169 + rem;
  } else {
    const int j = i - 507;
    const int a = j / 676;
    rem = j % 676;
    HW = 676;
    W = 26;
    const float AW[3] = {10.f, 23.f, 37.f};
    const float AH[3] = {14.f, 27.f, 58.f};
    aw = AW[a];
    ah = AH[a];
    p = feat2 + ((size_t)b * 255 + a * 85) * 676 + rem;
  }
  const int gy = rem / W, gx = rem % W;
  const float invW = 1.0f / (float)W;
  float cx = (sig_(p[0]) + (float)gx) * invW;
  float cy = (sig_(p[(size_t)HW]) + (float)gy) * invW;
  float bw = expf(p[(size_t)2 * HW]) * aw / 416.0f;
  float bh = expf(p[(size_t)3 * HW]) * ah / 416.0f;
  float obj = sig_(p[(size_t)4 * HW]);
  float best = p[(size_t)5 * HW];
  int lab = 0;
  for (int c = 1; c < 80; ++c) {
    float v = p[(size_t)(5 + c) * HW];
    if (v > best) {
      best = v;
      lab = c;
    }
  }
  float cc = sig_(best);
  float score = obj * cc;
  if (score < 0.1f) score = 0.0f;
  float* o = cand + (size_t)gid * 8;
  o[0] = (cy - bh * 0.5f) * 416.0f;
  o[1] = (cx - bw * 0.5f) * 416.0f;
  o[2] = (cy + bh * 0.5f) * 416.0f;
  o[3] = (cx + bw * 0.5f) * 416.0f;
  o[4] = obj;
  o[5] = cc;
  o[6] = (float)lab;
  o[7] = score;
  keys[gid] = ((u64)__float_as_uint(score) << 32) |
              (u64)(0xFFFFFFFFu - (unsigned)i);
}

// ---------------------------------------------------------------------------
// Exact top-300 via rank (distinct keys -> bijection): sel[rank]=idx.
// ---------------------------------------------------------------------------
__global__ __launch_bounds__(256) void rank_select_kernel(
    const u64* __restrict__ keys, int* __restrict__ sel) {
  const int b = blockIdx.y;
  __shared__ u64 k[NCAND];
  const u64* kb = keys + (size_t)b * NCAND;
  for (int t = threadIdx.x; t < NCAND; t += 256) k[t] = kb[t];
  __syncthreads();
  const int idx = blockIdx.x * 256 + threadIdx.x;
  if (idx >= NCAND) return;
  const u64 me = k[idx];
  int rank = 0;
#pragma unroll 4
  for (int j = 0; j < NCAND; j++) rank += (k[j] > me) ? 1 : 0;
  if (rank < NKEEP) sel[b * NKEEP + rank] = idx;
}

// ---------------------------------------------------------------------------
// Per-image NMS (same semantics as reference fori_loop; see round-7 notes).
// ---------------------------------------------------------------------------
__global__ __launch_bounds__(256) void nms_kernel(
    const float* __restrict__ cand, const int* __restrict__ sel,
    float* __restrict__ out) {
  const int b = blockIdx.x;
  const int tid = threadIdx.x;
  const float* cb = cand + (size_t)b * NCAND * 8;

  __shared__ float4 bxv[NKEEP];
  __shared__ float2 oc2[NKEEP];
  __shared__ int lv[NKEEP];
  __shared__ u64 msk[NKEEP][6];
  __shared__ u64 validw[5];
  __shared__ u64 keepw[5];

  for (int t = tid; t < NKEEP; t += 256) {
    const int idx = sel[b * NKEEP + t];
    const float* c = cb + (size_t)idx * 8;
    const float4 c0 = *(const float4*)c;
    const float4 c1 = *(const float4*)(c + 4);
    bxv[t] = c0;
    oc2[t] = make_float2(c1.x, c1.y);
    lv[t] = (int)c1.z | ((c1.w > 0.0f) ? 0x10000 : 0);
  }
  __syncthreads();

  {
    const u64 m1 = __ballot((lv[tid] & 0x10000) != 0);
    if ((tid & 63) == 0) validw[tid >> 6] = m1;
    const u64 m2 = __ballot(tid < 44 && (lv[tid + 256] & 0x10000) != 0);
    if (tid == 0) validw[4] = m2;
  }

  for (int t = tid; t < NKEEP; t += 256) {
    u64 w[5] = {0, 0, 0, 0, 0};
    const int lvt = lv[t];
    if ((lvt & 0x10000) && t + 1 < NKEEP) {
      const float4 a = bxv[t];
      const float aarea = (a.z - a.x) * (a.w - a.y);
      int lv1 = lv[t + 1];
      float4 bb1 = bxv[t + 1];
      int j2 = (t + 2 < NKEEP) ? t + 2 : NKEEP - 1;
      int lv2 = (t + 2 < NKEEP) ? lv[j2] : -1;
      float4 bb2 = bxv[j2];
      for (int j = t + 1; j < NKEEP; ++j) {
        const int lvj = lv1;
        const float4 bbj = bb1;
        lv1 = lv2;
        bb1 = bb2;
        const int jn = (j + 2 < NKEEP) ? j + 2 : NKEEP - 1;
        lv2 = (j + 2 < NKEEP) ? lv[jn] : -1;
        bb2 = bxv[jn];
        if (lvj == lvt) {
          const float ty = fmaxf(a.x, bbj.x), tx = fmaxf(a.y, bbj.y);
          const float ey = fminf(a.z, bbj.z), ex = fminf(a.w, bbj.w);
          const float dy = fmaxf(ey - ty, 0.0f), dx = fmaxf(ex - tx, 0.0f);
          const float inter = dy * dx;
          const float barea = (bbj.z - bbj.x) * (bbj.w - bbj.y);
          const float iou = inter / (aarea + barea - inter + 1e-9f);
          if (iou > 0.5f) w[j >> 6] |= 1ull << (j & 63);
        }
      }
    }
#pragma unroll
    for (int q = 0; q < 5; q++) msk[t][q] = w[q];
  }
  __syncthreads();

  if (tid < 64) {
    const int L = tid;
    u64 slot[5][5];
#pragma unroll
    for (int q = 0; q < 5; q++) {
      const int row = q * 64 + L;
#pragma unroll
      for (int w = 0; w < 5; w++)
        slot[q][w] = (row < NKEEP) ? msk[row][w] : 0ull;
    }
    u64 kw[5];
#pragma unroll
    for (int w = 0; w < 5; w++) kw[w] = validw[w];
#pragma unroll
    for (int q = 0; q < 5; q++) {
      const int nb = (q == 4) ? (NKEEP - 256) : 64;
      for (int bit = 0; bit < nb; ++bit) {
        u64 r[5];
#pragma unroll
        for (int w = 0; w < 5; w++) r[w] = __shfl(slot[q][w], bit, 64);
        const u64 m = 0ull - ((kw[q] >> bit) & 1ull);
#pragma unroll
        for (int w = 0; w < 5; w++) kw[w] &= ~(r[w] & m);
      }
    }
    if (L == 0) {
#pragma unroll
      for (int w = 0; w < 5; w++) keepw[w] = kw[w];
    }
  }
  __syncthreads();

  float* ob = out + (size_t)b * NKEEP * 7;
  for (int t = tid; t < NKEEP; t += 256) {
    const bool k = (keepw[t >> 6] >> (t & 63)) & 1ull;
    float* r = ob + (size_t)t * 7;
    if (k) {
      const float4 a = bxv[t];
      const float2 o2 = oc2[t];
      r[0] = a.x;
      r[1] = a.y;
      r[2] = a.z;
      r[3] = a.w;
      r[4] = o2.x;
      r[5] = o2.y;
      r[6] = (float)(lv[t] & 0xFFFF);
    } else {
      r[0] = 0.0f; r[1] = 0.0f; r[2] = 0.0f; r[3] = 0.0f;
      r[4] = 0.0f; r[5] = 0.0f; r[6] = 0.0f;
    }
  }
}

// ---------------------------------------------------------------------------
// Workspace (float offsets) — round-8 layout (lifetime-checked):
//   x1  : [0, 11075584)          x2/P: [11075584, 16613376)
//   P3  : [5537792, 11075584)    x3 : [0, 2768896)
//   x4  : [2768896, 4153344)     f2 : [4153344, 5532384)
//   x5  : [5532384, 6224608)     f1 : [6224608, 6569368)
//   w5r : [6224608, 7404256)     wh2r: [7404256, 7469536)
//   wh1r: [7469536, 7600096)
//   cd  : [6569368, 6731608)  keys: [6731608, 6772168)  sel: [6772168, 6774568)
// Peak = 16613376 floats = 66.5 MB.
// ---------------------------------------------------------------------------
extern "C" void kernel_launch(void* const* d_in, const int* in_sizes, int n_in,
                              void* d_out, int out_size, void* d_ws,
                              size_t ws_size, hipStream_t stream) {
  const float* images = (const float*)d_in[0];
  const float* w1 = (const float*)d_in[1];
  const float* b1 = (const float*)d_in[2];
  const float* w2 = (const float*)d_in[3];
  const float* b2 = (const float*)d_in[4];
  const float* w3 = (const float*)d_in[5];
  const float* b3 = (const float*)d_in[6];
  const float* w4 = (const float*)d_in[7];
  const float* b4 = (const float*)d_in[8];
  const float* w5 = (const float*)d_in[9];
  const float* b5 = (const float*)d_in[10];
  const float* wh1 = (const float*)d_in[11];
  const float* bh1 = (const float*)d_in[12];
  const float* wh2 = (const float*)d_in[13];
  const float* bh2 = (const float*)d_in[14];
  float* ws = (float*)d_ws;

  float* x1 = ws + 0;
  float* x2 = ws + 11075584;
  float* P3 = ws + 5537792;
  float* x3 = ws + 0;
  float* x4 = ws + 2768896;
  float* f2 = ws + 4153344;
  float* x5 = ws + 5532384;
  float* f1 = ws + 6224608;
  float* cd = ws + 6569368;
  u64* keys = (u64*)(ws + 6731608);
  int* sel = (int*)(ws + 6772168);
  float* P = ws + 11075584;
  float* w5r = ws + 6224608;
  float* wh2r = ws + 7404256;
  float* wh1r = ws + 7469536;

  // conv1: 2720 blocks
  k_conv1<<<dim3(85, 4, 8), 256, 0, stream>>>(images, w1, b1, x1);
  // conv2: 1408 blocks
  k_conv2<<<dim3(22, 8, 8), 256, 0, stream>>>(x1, w2, b2, x2);
  // conv3: split-K x2 -> 1536 blocks
  k_conv3<<<dim3(6, 16, 16), 256, 0, stream>>>(x2, w3, nullptr, P3);
  reduce_bias<2, true><<<(2768896 + 255) / 256, 256, 0, stream>>>(P3, b3, x3, 128, 2704, 2768896);
  // repack w5/wh2/wh1 (P3 dead now)
  k_repack<<<(1375488 + 255) / 256, 256, 0, stream>>>(w5, wh2, wh1, w5r, wh2r, wh1r);
  // conv4: split-K x4 -> 2048 blocks
  k_conv4<<<dim3(2, 32, 32), 256, 0, stream>>>(x3, w4, nullptr, P);
  reduce_bias<4, true><<<(1384448 + 255) / 256, 256, 0, stream>>>(P, b4, x4, 256, 676, 1384448);
  // head2: split-K x4 -> 1440 blocks
  k_head2<<<dim3(3, 15, 32), 256, 0, stream>>>(x4, wh2r, P);
  reduce_bias<4, false><<<(1379040 + 255) / 256, 256, 0, stream>>>(P, bh2, f2, 255, 676, 1379040);
  // conv5: split-K x8 -> 4096 blocks, LDS-staged weights
  k_conv5<<<dim3(1, 64, 64), 256, 0, stream>>>(x4, w5r, P);
  reduce_bias<8, true><<<(692224 + 255) / 256, 256, 0, stream>>>(P, b5, x5, 512, 169, 692224);
  // head1: split-K x16 -> 1920 blocks
  k_head1<<<dim3(1, 15, 128), 256, 0, stream>>>(x5, wh1r, P);
  reduce_bias<16, false><<<(344760 + 255) / 256, 256, 0, stream>>>(P, bh1, f1, 255, 169, 344760);

  decode_kernel<<<80, 256, 0, stream>>>(f1, f2, cd, keys);
  rank_select_kernel<<<dim3(10, 8), 256, 0, stream>>>(keys, sel);
  nms_kernel<<<8, 256, 0, stream>>>(cd, sel, (float*)d_out);
}

// Round 12
// 616.824 us; speedup vs baseline: 1.2308x; 1.0574x over previous
//
#include <hip/hip_runtime.h>
#include <stdint.h>

typedef unsigned long long u64;

__device__ __forceinline__ float sig_(float x) { return 1.0f / (1.0f + expf(-x)); }

#define NCAND 2535
#define NKEEP 300

// ---------------------------------------------------------------------------
// Pair-spatial 3x3 stride-2 conv body (2 horizontal outputs/thread), SAME
// padding (0 before / 1 after), OCT oc/thread, split-K, depth-2 register
// prefetch (round-8 proven form). Explicit block coords for merged launches.
// ---------------------------------------------------------------------------
template <int CIN, int HIN, int WIN, int OCT, int SPLIT, int COUT>
__device__ __forceinline__ void conv_p2_body(
    const float* __restrict__ in, const float* __restrict__ wgt,
    const float* __restrict__ bias, float* __restrict__ out, int bx, int g,
    int bz) {
  constexpr int HOUT = HIN / 2, WOUT = WIN / 2, WP = WOUT / 2;
  constexpr int HWIN = HIN * WIN, HWOUT = HOUT * WOUT;
  constexpr int CS = CIN / SPLIT;
  static_assert(WOUT % 2 == 0 && WIN % 4 == 0, "pair layout");
  const int b = bz / SPLIT, s = bz % SPLIT;
  const int oc0 = g * OCT;
  const int sp = bx * 256 + threadIdx.x;
  if (sp >= HOUT * WP) return;
  const int oy = sp / WP, oxp = sp % WP;
  const int ox0 = oxp * 2;
  const int iy0 = oy * 2, ix0 = oxp * 4;
  const bool okY = (iy0 + 2 < HIN);
  const bool c4v = (ix0 + 4 < WIN);
  const float* inb =
      in + ((size_t)b * CIN + s * CS) * HWIN + (size_t)iy0 * WIN + ix0;
  const float* wbase = wgt + ((size_t)oc0 * CIN + s * CS) * 9;

  float acc0[OCT], acc1[OCT];
#pragma unroll
  for (int u = 0; u < OCT; u++) {
    acc0[u] = 0.0f;
    acc1[u] = 0.0f;
  }

  auto load15 = [&](float v[15], const float* ip) {
#pragma unroll
    for (int ky = 0; ky < 3; ky++) {
      const bool rok = (ky < 2) || okY;
      const float* rp = ip + ky * WIN;
      float4 p = make_float4(0.f, 0.f, 0.f, 0.f);
      float c4 = 0.f;
      if (rok) {
        p = *(const float4*)rp;  // 16B-aligned: ix0%4==0, WIN%4==0
        if (c4v) c4 = rp[4];
      }
      v[ky * 5 + 0] = p.x;
      v[ky * 5 + 1] = p.y;
      v[ky * 5 + 2] = p.z;
      v[ky * 5 + 3] = p.w;
      v[ky * 5 + 4] = c4;
    }
  };
  auto fmablk = [&](const float v[15], int ci) {
#pragma unroll
    for (int u = 0; u < OCT; u++) {
#pragma unroll
      for (int ky = 0; ky < 3; ky++) {
#pragma unroll
        for (int kx = 0; kx < 3; kx++) {
          const float w =
              wbase[(size_t)ci * 9 + (size_t)u * CIN * 9 + ky * 3 + kx];
          acc0[u] = fmaf(v[ky * 5 + kx], w, acc0[u]);
          acc1[u] = fmaf(v[ky * 5 + kx + 2], w, acc1[u]);
        }
      }
    }
  };

  float vA[15], vB[15];
  load15(vA, inb);
  if (CS > 1) load15(vB, inb + HWIN);
  for (int ci = 0; ci < CS; ci += 2) {
    float nA[15];
    if (ci + 2 < CS) load15(nA, inb + (size_t)(ci + 2) * HWIN);
    fmablk(vA, ci);
    float nB[15];
    if (ci + 3 < CS) load15(nB, inb + (size_t)(ci + 3) * HWIN);
    if (ci + 1 < CS) fmablk(vB, ci + 1);
    if (ci + 2 < CS) {
#pragma unroll
      for (int k = 0; k < 15; k++) vA[k] = nA[k];
    }
    if (ci + 3 < CS) {
#pragma unroll
      for (int k = 0; k < 15; k++) vB[k] = nB[k];
    }
  }

  const size_t obase =
      (SPLIT == 1 ? (size_t)b * COUT : (size_t)(s * 8 + b) * COUT);
  float* ob = out + (obase + oc0) * HWOUT + (size_t)oy * WOUT + ox0;
  if (SPLIT == 1) {
#pragma unroll
    for (int u = 0; u < OCT; u++) {
      float r0 = acc0[u] + bias[oc0 + u];
      float r1 = acc1[u] + bias[oc0 + u];
      r0 = r0 > 0.0f ? r0 : 0.1f * r0;
      r1 = r1 > 0.0f ? r1 : 0.1f * r1;
      *(float2*)(ob + (size_t)u * HWOUT) = make_float2(r0, r1);
    }
  } else {
#pragma unroll
    for (int u = 0; u < OCT; u++)
      *(float2*)(ob + (size_t)u * HWOUT) = make_float2(acc0[u], acc1[u]);
  }
}

// Standalone per-layer wrappers (round-8 grids).
__global__ __launch_bounds__(256) void k_conv1(const float* __restrict__ i,
                                               const float* __restrict__ w,
                                               const float* __restrict__ b,
                                               float* __restrict__ o) {
  conv_p2_body<3, 416, 416, 8, 1, 32>(i, w, b, o, blockIdx.x, blockIdx.y,
                                      blockIdx.z);
}
__global__ __launch_bounds__(256) void k_conv2(const float* __restrict__ i,
                                               const float* __restrict__ w,
                                               const float* __restrict__ b,
                                               float* __restrict__ o) {
  conv_p2_body<32, 208, 208, 8, 1, 64>(i, w, b, o, blockIdx.x, blockIdx.y,
                                       blockIdx.z);
}
__global__ __launch_bounds__(256) void k_conv3(const float* __restrict__ i,
                                               const float* __restrict__ w,
                                               const float* __restrict__ b,
                                               float* __restrict__ o) {
  conv_p2_body<64, 104, 104, 8, 2, 128>(i, w, b, o, blockIdx.x, blockIdx.y,
                                        blockIdx.z);
}

// ---------------------------------------------------------------------------
// conv4 (2048 blocks) merged with grid-stride repack of w5/wh2/wh1 (1024
// blocks). Repack is independent of conv4; P3 is dead by this launch.
// ---------------------------------------------------------------------------
__global__ __launch_bounds__(256) void k_conv4_repack(
    const float* __restrict__ x3, const float* __restrict__ w4,
    float* __restrict__ P, const float* __restrict__ w5,
    const float* __restrict__ wh2, const float* __restrict__ wh1,
    float* __restrict__ w5r, float* __restrict__ wh2r,
    float* __restrict__ wh1r) {
  const int fb = blockIdx.x;
  if (fb < 2048) {
    conv_p2_body<128, 52, 52, 8, 4, 256>(x3, w4, nullptr, P, fb % 2,
                                         (fb / 2) % 32, fb / 64);
    return;
  }
  const int base = (fb - 2048) * 256 + threadIdx.x;
  for (int gid = base; gid < 1375488; gid += 1024 * 256) {
    if (gid < 1179648) {  // w5: COUT=512, CIN=256, CS=32, OCT=8
      const int oc = gid / (256 * 9), r = gid % (256 * 9);
      const int ci = r / 9, k = r % 9;
      const int g = oc / 8, u = oc % 8, s = ci / 32, cl = ci % 32;
      w5r[(((size_t)(g * 8 + s) * 32 + cl) * 8 + u) * 9 + k] = w5[gid];
    } else if (gid < 1179648 + 65280) {  // wh2: 255x256, SPLIT=2 -> CS=128
      const int t = gid - 1179648;
      const int oc = t / 256, ci = t % 256;
      const int g = oc / 17, u = oc % 17, s = ci / 128, cl = ci % 128;
      wh2r[((size_t)(g * 2 + s) * 128 + cl) * 17 + u] = wh2[t];
    } else {  // wh1: 255x512, SPLIT=16 -> CS=32
      const int t = gid - 1179648 - 65280;
      const int oc = t / 512, ci = t % 512;
      const int g = oc / 17, u = oc % 17, s = ci / 32, cl = ci % 32;
      wh1r[((size_t)(g * 16 + s) * 32 + cl) * 17 + u] = wh1[t];
    }
  }
}

// ---------------------------------------------------------------------------
// 1x1 head body (round-8 proven form), explicit block coords.
// ---------------------------------------------------------------------------
template <int CIN, int OCT, int SPLIT>
__device__ __forceinline__ void head_body(const float* __restrict__ in,
                                          const float* __restrict__ wgt,
                                          float* __restrict__ out, int HW,
                                          int bx, int g, int bz) {
  constexpr int CS = CIN / SPLIT;  // multiple of 8
  const int sp = bx * 256 + threadIdx.x;
  if (sp >= HW) return;
  const int oc0 = g * OCT;
  const int b = bz / SPLIT, s = bz % SPLIT;
  const float* ip = in + ((size_t)b * CIN + s * CS) * HW + sp;
  const float* wb = wgt + (size_t)(g * SPLIT + s) * CS * OCT;
  float acc[OCT];
#pragma unroll
  for (int u = 0; u < OCT; u++) acc[u] = 0.0f;

  auto fma4 = [&](const float v[4], int base) {
#pragma unroll
    for (int j = 0; j < 4; j++) {
#pragma unroll
      for (int u = 0; u < OCT; u++)
        acc[u] = fmaf(v[j], wb[(size_t)(base + j) * OCT + u], acc[u]);
    }
  };

  float vA[4], vB[4];
#pragma unroll
  for (int j = 0; j < 4; j++) {
    vA[j] = ip[(size_t)j * HW];
    vB[j] = ip[(size_t)(4 + j) * HW];
  }
  for (int c0 = 0; c0 < CS; c0 += 8) {
    float nA[4];
    if (c0 + 8 < CS) {
#pragma unroll
      for (int j = 0; j < 4; j++) nA[j] = ip[(size_t)(c0 + 8 + j) * HW];
    }
    fma4(vA, c0);
    float nB[4];
    if (c0 + 12 < CS) {
#pragma unroll
      for (int j = 0; j < 4; j++) nB[j] = ip[(size_t)(c0 + 12 + j) * HW];
    }
    fma4(vB, c0 + 4);
    if (c0 + 8 < CS) {
#pragma unroll
      for (int j = 0; j < 4; j++) vA[j] = nA[j];
    }
    if (c0 + 12 < CS) {
#pragma unroll
      for (int j = 0; j < 4; j++) vB[j] = nB[j];
    }
  }
#pragma unroll
  for (int u = 0; u < OCT; u++)
    out[((size_t)(s * 8 + b) * 255 + oc0 + u) * HW + sp] = acc[u];
}

// ---------------------------------------------------------------------------
// conv5 body (round-8 proven form), explicit g/z coords.
// ---------------------------------------------------------------------------
__device__ __forceinline__ void conv5_body(const float* __restrict__ in,
                                           const float* __restrict__ wgt,
                                           float* __restrict__ out, int g,
                                           int z) {
  constexpr int CIN = 256, HIN = 26, WIN = 26, OCT = 8, SPLIT = 8;
  constexpr int HWIN = 676, HWOUT = 169, WOUT = 13;
  constexpr int CS = CIN / SPLIT;  // 32
  const int b = z / SPLIT, s = z % SPLIT;
  const int oc0 = g * OCT;
  constexpr int COUT = 512;
  const int sp = threadIdx.x;
  if (sp >= HWOUT) return;
  const int oy = sp / WOUT, ox = sp % WOUT;
  const int iy0 = oy * 2, ix0 = ox * 2;
  const bool okY = (iy0 + 2 < HIN);
  const bool okX = (ix0 + 2 < WIN);
  const float* inb =
      in + ((size_t)b * CIN + s * CS) * HWIN + (size_t)iy0 * WIN + ix0;
  const float* wbase = wgt + (size_t)(g * SPLIT + s) * CS * OCT * 9;

  float acc[OCT];
#pragma unroll
  for (int u = 0; u < OCT; u++) acc[u] = 0.0f;

  auto load9 = [&](float v[9], const float* ip) {
#pragma unroll
    for (int ky = 0; ky < 3; ky++) {
      const bool rok = (ky < 2) || okY;
      const float* rp = ip + ky * WIN;
      float a0 = 0.f, a1 = 0.f, a2 = 0.f;
      if (rok) {
        const float2 p = *(const float2*)rp;  // 8B-aligned
        a0 = p.x;
        a1 = p.y;
        if (okX) a2 = rp[2];
      }
      v[ky * 3 + 0] = a0;
      v[ky * 3 + 1] = a1;
      v[ky * 3 + 2] = a2;
    }
  };
  auto fmablk = [&](const float v[9], int ci) {
#pragma unroll
    for (int u = 0; u < OCT; u++) {
#pragma unroll
      for (int k = 0; k < 9; k++)
        acc[u] = fmaf(v[k], wbase[(size_t)ci * OCT * 9 + u * 9 + k], acc[u]);
    }
  };

  float vA[9], vB[9];
  load9(vA, inb);
  load9(vB, inb + HWIN);
  for (int ci = 0; ci < CS; ci += 2) {
    float nA[9];
    if (ci + 2 < CS) load9(nA, inb + (size_t)(ci + 2) * HWIN);
    fmablk(vA, ci);
    float nB[9];
    if (ci + 3 < CS) load9(nB, inb + (size_t)(ci + 3) * HWIN);
    fmablk(vB, ci + 1);
    if (ci + 2 < CS) {
#pragma unroll
      for (int k = 0; k < 9; k++) vA[k] = nA[k];
    }
    if (ci + 3 < CS) {
#pragma unroll
      for (int k = 0; k < 9; k++) vB[k] = nB[k];
    }
  }

  float* ob = out + ((size_t)(s * 8 + b) * COUT + oc0) * HWOUT + sp;
#pragma unroll
  for (int u = 0; u < OCT; u++) ob[(size_t)u * HWOUT] = acc[u];
}

// ---------------------------------------------------------------------------
// Merged launch: conv5 (blocks 0..4095) + head2 SPLIT=2 (blocks 4096..4815).
// Both depend only on x4; disjoint partial regions (P5 vs Ph2).
// ---------------------------------------------------------------------------
__global__ __launch_bounds__(256) void k_h2c5(const float* __restrict__ x4,
                                              const float* __restrict__ w5r,
                                              const float* __restrict__ wh2r,
                                              float* __restrict__ P5,
                                              float* __restrict__ Ph2) {
  const int fb = blockIdx.x;
  if (fb < 4096) {
    conv5_body(x4, w5r, P5, fb & 63, fb >> 6);
  } else {
    const int id = fb - 4096;  // 720 blocks: x in [0,3), g in [0,15), z in [0,16)
    head_body<256, 17, 2>(x4, wh2r, Ph2, 676, id % 3, (id / 3) % 15, id / 45);
  }
}

__global__ __launch_bounds__(256) void k_head1(const float* __restrict__ i,
                                               const float* __restrict__ w,
                                               float* __restrict__ o) {
  head_body<512, 17, 16>(i, w, o, 169, blockIdx.x, blockIdx.y, blockIdx.z);
}

// ---------------------------------------------------------------------------
// Reduce SPLIT partials (slice-major, deterministic) + bias (+ lrelu).
// ---------------------------------------------------------------------------
template <int SPLIT, bool LRELU>
__device__ __forceinline__ void reduce_body(const float* __restrict__ P,
                                            const float* __restrict__ bias,
                                            float* __restrict__ out, int COUT,
                                            int HWOUT, int N, int gid) {
  if (gid >= N) return;
  float a = 0.0f;
#pragma unroll
  for (int s = 0; s < SPLIT; s++) a += P[(size_t)s * N + gid];
  const int oc = (gid / HWOUT) % COUT;
  a += bias[oc];
  if (LRELU) a = a > 0.0f ? a : 0.1f * a;
  out[gid] = a;
}

template <int SPLIT, bool LRELU>
__global__ __launch_bounds__(256) void reduce_bias(
    const float* __restrict__ P, const float* __restrict__ bias,
    float* __restrict__ out, int COUT, int HWOUT, int N) {
  reduce_body<SPLIT, LRELU>(P, bias, out, COUT, HWOUT, N,
                            blockIdx.x * 256 + threadIdx.x);
}

// Merged reduce for conv5 (SPLIT=8, lrelu -> x5) + head2 (SPLIT=2 -> f2).
__global__ __launch_bounds__(256) void k_reduce_h2c5(
    const float* __restrict__ P5, const float* __restrict__ Ph2,
    const float* __restrict__ b5, const float* __restrict__ bh2,
    float* __restrict__ x5, float* __restrict__ f2) {
  const int fb = blockIdx.x;
  if (fb < 2704) {
    reduce_body<8, true>(P5, b5, x5, 512, 169, 692224,
                         fb * 256 + threadIdx.x);
  } else {
    reduce_body<2, false>(Ph2, bh2, f2, 255, 676, 1379040,
                          (fb - 2704) * 256 + threadIdx.x);
  }
}

// ---------------------------------------------------------------------------
// Decode both heads -> cand[b][i][8] = {y1,x1,y2,x2,obj,cc,label,score} and
// packed keys (score_bits<<32)|(0xFFFFFFFF-i) matching jax.lax.top_k order.
// ---------------------------------------------------------------------------
__global__ __launch_bounds__(256) void decode_kernel(
    const float* __restrict__ feat1, const float* __restrict__ feat2,
    float* __restrict__ cand, u64* __restrict__ keys) {
  const int gid = blockIdx.x * 256 + threadIdx.x;
  if (gid >= 8 * NCAND) return;
  const int b = gid / NCAND;
  const int i = gid % NCAND;
  const float* p;
  int rem, HW, W;
  float aw, ah;
  if (i < 507) {
    const int a = i / 169;
    rem = i % 169;
    HW = 169;
    W = 13;
    const float AW[3] = {81.f, 135.f, 344.f};
    const float AH[3] = {82.f, 169.f, 319.f};
    aw = AW[a];
    ah = AH[a];
    p = feat1 + ((size_t)b * 255 + a * 85) * 169 + rem;
  } else {
    const int j = i - 507;
    const int a = j / 676;
    rem = j % 676;
    HW = 676;
    W = 26;
    const float AW[3] = {10.f, 23.f, 37.f};
    const float AH[3] = {14.f, 27.f, 58.f};
    aw = AW[a];
    ah = AH[a];
    p = feat2 + ((size_t)b * 255 + a * 85) * 676 + rem;
  }
  const int gy = rem / W, gx = rem % W;
  const float invW = 1.0f / (float)W;
  float cx = (sig_(p[0]) + (float)gx) * invW;
  float cy = (sig_(p[(size_t)HW]) + (float)gy) * invW;
  float bw = expf(p[(size_t)2 * HW]) * aw / 416.0f;
  float bh = expf(p[(size_t)3 * HW]) * ah / 416.0f;
  float obj = sig_(p[(size_t)4 * HW]);
  float best = p[(size_t)5 * HW];
  int lab = 0;
  for (int c = 1; c < 80; ++c) {
    float v = p[(size_t)(5 + c) * HW];
    if (v > best) {
      best = v;
      lab = c;
    }
  }
  float cc = sig_(best);
  float score = obj * cc;
  if (score < 0.1f) score = 0.0f;
  float* o = cand + (size_t)gid * 8;
  o[0] = (cy - bh * 0.5f) * 416.0f;
  o[1] = (cx - bw * 0.5f) * 416.0f;
  o[2] = (cy + bh * 0.5f) * 416.0f;
  o[3] = (cx + bw * 0.5f) * 416.0f;
  o[4] = obj;
  o[5] = cc;
  o[6] = (float)lab;
  o[7] = score;
  keys[gid] = ((u64)__float_as_uint(score) << 32) |
              (u64)(0xFFFFFFFFu - (unsigned)i);
}

// ---------------------------------------------------------------------------
// Exact top-300 via rank (distinct keys -> bijection): sel[rank]=idx.
// ---------------------------------------------------------------------------
__global__ __launch_bounds__(256) void rank_select_kernel(
    const u64* __restrict__ keys, int* __restrict__ sel) {
  const int b = blockIdx.y;
  __shared__ u64 k[NCAND];
  const u64* kb = keys + (size_t)b * NCAND;
  for (int t = threadIdx.x; t < NCAND; t += 256) k[t] = kb[t];
  __syncthreads();
  const int idx = blockIdx.x * 256 + threadIdx.x;
  if (idx >= NCAND) return;
  const u64 me = k[idx];
  int rank = 0;
#pragma unroll 4
  for (int j = 0; j < NCAND; j++) rank += (k[j] > me) ? 1 : 0;
  if (rank < NKEEP) sel[b * NKEEP + rank] = idx;
}

// ---------------------------------------------------------------------------
// Per-image NMS (same semantics as reference fori_loop; see round-7 notes).
// ---------------------------------------------------------------------------
__global__ __launch_bounds__(256) void nms_kernel(
    const float* __restrict__ cand, const int* __restrict__ sel,
    float* __restrict__ out) {
  const int b = blockIdx.x;
  const int tid = threadIdx.x;
  const float* cb = cand + (size_t)b * NCAND * 8;

  __shared__ float4 bxv[NKEEP];
  __shared__ float2 oc2[NKEEP];
  __shared__ int lv[NKEEP];
  __shared__ u64 msk[NKEEP][6];
  __shared__ u64 validw[5];
  __shared__ u64 keepw[5];

  for (int t = tid; t < NKEEP; t += 256) {
    const int idx = sel[b * NKEEP + t];
    const float* c = cb + (size_t)idx * 8;
    const float4 c0 = *(const float4*)c;
    const float4 c1 = *(const float4*)(c + 4);
    bxv[t] = c0;
    oc2[t] = make_float2(c1.x, c1.y);
    lv[t] = (int)c1.z | ((c1.w > 0.0f) ? 0x10000 : 0);
  }
  __syncthreads();

  {
    const u64 m1 = __ballot((lv[tid] & 0x10000) != 0);
    if ((tid & 63) == 0) validw[tid >> 6] = m1;
    const u64 m2 = __ballot(tid < 44 && (lv[tid + 256] & 0x10000) != 0);
    if (tid == 0) validw[4] = m2;
  }

  for (int t = tid; t < NKEEP; t += 256) {
    u64 w[5] = {0, 0, 0, 0, 0};
    const int lvt = lv[t];
    if ((lvt & 0x10000) && t + 1 < NKEEP) {
      const float4 a = bxv[t];
      const float aarea = (a.z - a.x) * (a.w - a.y);
      int lv1 = lv[t + 1];
      float4 bb1 = bxv[t + 1];
      int j2 = (t + 2 < NKEEP) ? t + 2 : NKEEP - 1;
      int lv2 = (t + 2 < NKEEP) ? lv[j2] : -1;
      float4 bb2 = bxv[j2];
      for (int j = t + 1; j < NKEEP; ++j) {
        const int lvj = lv1;
        const float4 bbj = bb1;
        lv1 = lv2;
        bb1 = bb2;
        const int jn = (j + 2 < NKEEP) ? j + 2 : NKEEP - 1;
        lv2 = (j + 2 < NKEEP) ? lv[jn] : -1;
        bb2 = bxv[jn];
        if (lvj == lvt) {
          const float ty = fmaxf(a.x, bbj.x), tx = fmaxf(a.y, bbj.y);
          const float ey = fminf(a.z, bbj.z), ex = fminf(a.w, bbj.w);
          const float dy = fmaxf(ey - ty, 0.0f), dx = fmaxf(ex - tx, 0.0f);
          const float inter = dy * dx;
          const float barea = (bbj.z - bbj.x) * (bbj.w - bbj.y);
          const float iou = inter / (aarea + barea - inter + 1e-9f);
          if (iou > 0.5f) w[j >> 6] |= 1ull << (j & 63);
        }
      }
    }
#pragma unroll
    for (int q = 0; q < 5; q++) msk[t][q] = w[q];
  }
  __syncthreads();

  if (tid < 64) {
    const int L = tid;
    u64 slot[5][5];
#pragma unroll
    for (int q = 0; q < 5; q++) {
      const int row = q * 64 + L;
#pragma unroll
      for (int w = 0; w < 5; w++)
        slot[q][w] = (row < NKEEP) ? msk[row][w] : 0ull;
    }
    u64 kw[5];
#pragma unroll
    for (int w = 0; w < 5; w++) kw[w] = validw[w];
#pragma unroll
    for (int q = 0; q < 5; q++) {
      const int nb = (q == 4) ? (NKEEP - 256) : 64;
      for (int bit = 0; bit < nb; ++bit) {
        u64 r[5];
#pragma unroll
        for (int w = 0; w < 5; w++) r[w] = __shfl(slot[q][w], bit, 64);
        const u64 m = 0ull - ((kw[q] >> bit) & 1ull);
#pragma unroll
        for (int w = 0; w < 5; w++) kw[w] &= ~(r[w] & m);
      }
    }
    if (L == 0) {
#pragma unroll
      for (int w = 0; w < 5; w++) keepw[w] = kw[w];
    }
  }
  __syncthreads();

  float* ob = out + (size_t)b * NKEEP * 7;
  for (int t = tid; t < NKEEP; t += 256) {
    const bool k = (keepw[t >> 6] >> (t & 63)) & 1ull;
    float* r = ob + (size_t)t * 7;
    if (k) {
      const float4 a = bxv[t];
      const float2 o2 = oc2[t];
      r[0] = a.x;
      r[1] = a.y;
      r[2] = a.z;
      r[3] = a.w;
      r[4] = o2.x;
      r[5] = o2.y;
      r[6] = (float)(lv[t] & 0xFFFF);
    } else {
      r[0] = 0.0f; r[1] = 0.0f; r[2] = 0.0f; r[3] = 0.0f;
      r[4] = 0.0f; r[5] = 0.0f; r[6] = 0.0f;
    }
  }
}

// ---------------------------------------------------------------------------
// Workspace (float offsets), lifetime-checked for the merged schedule:
//   x1  : [0, 11075584)          x2/P5: [11075584, 16613376)
//   P3  : [5537792, 11075584)    x3 : [0, 2768896)
//   x4  : [2768896, 4153344)     f2 : [4153344, 5532384)
//   x5  : [5532384, 6224608)     f1 : [6224608, 6569368)
//   w5r : [6224608, 7404256)     wh2r: [7404256, 7469536)
//   wh1r: [7469536, 7600096)     Ph2 : [7600096, 10358176)  (dead x1/P3 zone)
//   cd  : [6569368, 6731608)  keys: [6731608, 6772168)  sel: [6772168, 6774568)
// Peak = 16613376 floats = 66.5 MB (unchanged).
// ---------------------------------------------------------------------------
extern "C" void kernel_launch(void* const* d_in, const int* in_sizes, int n_in,
                              void* d_out, int out_size, void* d_ws,
                              size_t ws_size, hipStream_t stream) {
  const float* images = (const float*)d_in[0];
  const float* w1 = (const float*)d_in[1];
  const float* b1 = (const float*)d_in[2];
  const float* w2 = (const float*)d_in[3];
  const float* b2 = (const float*)d_in[4];
  const float* w3 = (const float*)d_in[5];
  const float* b3 = (const float*)d_in[6];
  const float* w4 = (const float*)d_in[7];
  const float* b4 = (const float*)d_in[8];
  const float* w5 = (const float*)d_in[9];
  const float* b5 = (const float*)d_in[10];
  const float* wh1 = (const float*)d_in[11];
  const float* bh1 = (const float*)d_in[12];
  const float* wh2 = (const float*)d_in[13];
  const float* bh2 = (const float*)d_in[14];
  float* ws = (float*)d_ws;

  float* x1 = ws + 0;
  float* x2 = ws + 11075584;
  float* P3 = ws + 5537792;
  float* x3 = ws + 0;
  float* x4 = ws + 2768896;
  float* f2 = ws + 4153344;
  float* x5 = ws + 5532384;
  float* f1 = ws + 6224608;
  float* cd = ws + 6569368;
  u64* keys = (u64*)(ws + 6731608);
  int* sel = (int*)(ws + 6772168);
  float* P = ws + 11075584;     // conv4 + conv5 + head1 partials
  float* w5r = ws + 6224608;
  float* wh2r = ws + 7404256;
  float* wh1r = ws + 7469536;
  float* Ph2 = ws + 7600096;

  // conv1: 2720 blocks
  k_conv1<<<dim3(85, 4, 8), 256, 0, stream>>>(images, w1, b1, x1);
  // conv2: 1408 blocks
  k_conv2<<<dim3(22, 8, 8), 256, 0, stream>>>(x1, w2, b2, x2);
  // conv3: split-K x2 -> 1536 blocks
  k_conv3<<<dim3(6, 16, 16), 256, 0, stream>>>(x2, w3, nullptr, P3);
  reduce_bias<2, true><<<(2768896 + 255) / 256, 256, 0, stream>>>(P3, b3, x3, 128, 2704, 2768896);
  // conv4 (2048) + repack (1024) in one launch
  k_conv4_repack<<<3072, 256, 0, stream>>>(x3, w4, P, w5, wh2, wh1, w5r, wh2r, wh1r);
  reduce_bias<4, true><<<(1384448 + 255) / 256, 256, 0, stream>>>(P, b4, x4, 256, 676, 1384448);
  // conv5 (4096) + head2 SPLIT=2 (720) in one launch
  k_h2c5<<<4816, 256, 0, stream>>>(x4, w5r, wh2r, P, Ph2);
  // merged reduce: conv5 -> x5 (lrelu), head2 -> f2
  k_reduce_h2c5<<<2704 + 5388, 256, 0, stream>>>(P, Ph2, b5, bh2, x5, f2);
  // head1: split-K x16 -> 1920 blocks
  k_head1<<<dim3(1, 15, 128), 256, 0, stream>>>(x5, wh1r, P);
  reduce_bias<16, false><<<(344760 + 255) / 256, 256, 0, stream>>>(P, bh1, f1, 255, 169, 344760);

  decode_kernel<<<80, 256, 0, stream>>>(f1, f2, cd, keys);
  rank_select_kernel<<<dim3(10, 8), 256, 0, stream>>>(keys, sel);
  nms_kernel<<<8, 256, 0, stream>>>(cd, sel, (float*)d_out);
}

// Round 13
// 594.904 us; speedup vs baseline: 1.2762x; 1.0368x over previous
//
#include <hip/hip_runtime.h>
#include <stdint.h>

typedef unsigned long long u64;

__device__ __forceinline__ float sig_(float x) { return 1.0f / (1.0f + expf(-x)); }

#define NCAND 2535
#define NKEEP 300

// ---------------------------------------------------------------------------
// Pair-spatial 3x3 stride-2 conv body (round-8 proven form), explicit coords.
// ---------------------------------------------------------------------------
template <int CIN, int HIN, int WIN, int OCT, int SPLIT, int COUT>
__device__ __forceinline__ void conv_p2_body(
    const float* __restrict__ in, const float* __restrict__ wgt,
    const float* __restrict__ bias, float* __restrict__ out, int bx, int g,
    int bz) {
  constexpr int HOUT = HIN / 2, WOUT = WIN / 2, WP = WOUT / 2;
  constexpr int HWIN = HIN * WIN, HWOUT = HOUT * WOUT;
  constexpr int CS = CIN / SPLIT;
  static_assert(WOUT % 2 == 0 && WIN % 4 == 0, "pair layout");
  const int b = bz / SPLIT, s = bz % SPLIT;
  const int oc0 = g * OCT;
  const int sp = bx * 256 + threadIdx.x;
  if (sp >= HOUT * WP) return;
  const int oy = sp / WP, oxp = sp % WP;
  const int ox0 = oxp * 2;
  const int iy0 = oy * 2, ix0 = oxp * 4;
  const bool okY = (iy0 + 2 < HIN);
  const bool c4v = (ix0 + 4 < WIN);
  const float* inb =
      in + ((size_t)b * CIN + s * CS) * HWIN + (size_t)iy0 * WIN + ix0;
  const float* wbase = wgt + ((size_t)oc0 * CIN + s * CS) * 9;

  float acc0[OCT], acc1[OCT];
#pragma unroll
  for (int u = 0; u < OCT; u++) {
    acc0[u] = 0.0f;
    acc1[u] = 0.0f;
  }

  auto load15 = [&](float v[15], const float* ip) {
#pragma unroll
    for (int ky = 0; ky < 3; ky++) {
      const bool rok = (ky < 2) || okY;
      const float* rp = ip + ky * WIN;
      float4 p = make_float4(0.f, 0.f, 0.f, 0.f);
      float c4 = 0.f;
      if (rok) {
        p = *(const float4*)rp;  // 16B-aligned: ix0%4==0, WIN%4==0
        if (c4v) c4 = rp[4];
      }
      v[ky * 5 + 0] = p.x;
      v[ky * 5 + 1] = p.y;
      v[ky * 5 + 2] = p.z;
      v[ky * 5 + 3] = p.w;
      v[ky * 5 + 4] = c4;
    }
  };
  auto fmablk = [&](const float v[15], int ci) {
#pragma unroll
    for (int u = 0; u < OCT; u++) {
#pragma unroll
      for (int ky = 0; ky < 3; ky++) {
#pragma unroll
        for (int kx = 0; kx < 3; kx++) {
          const float w =
              wbase[(size_t)ci * 9 + (size_t)u * CIN * 9 + ky * 3 + kx];
          acc0[u] = fmaf(v[ky * 5 + kx], w, acc0[u]);
          acc1[u] = fmaf(v[ky * 5 + kx + 2], w, acc1[u]);
        }
      }
    }
  };

  float vA[15], vB[15];
  load15(vA, inb);
  if (CS > 1) load15(vB, inb + HWIN);
  for (int ci = 0; ci < CS; ci += 2) {
    float nA[15];
    if (ci + 2 < CS) load15(nA, inb + (size_t)(ci + 2) * HWIN);
    fmablk(vA, ci);
    float nB[15];
    if (ci + 3 < CS) load15(nB, inb + (size_t)(ci + 3) * HWIN);
    if (ci + 1 < CS) fmablk(vB, ci + 1);
    if (ci + 2 < CS) {
#pragma unroll
      for (int k = 0; k < 15; k++) vA[k] = nA[k];
    }
    if (ci + 3 < CS) {
#pragma unroll
      for (int k = 0; k < 15; k++) vB[k] = nB[k];
    }
  }

  const size_t obase =
      (SPLIT == 1 ? (size_t)b * COUT : (size_t)(s * 8 + b) * COUT);
  float* ob = out + (obase + oc0) * HWOUT + (size_t)oy * WOUT + ox0;
  if (SPLIT == 1) {
#pragma unroll
    for (int u = 0; u < OCT; u++) {
      float r0 = acc0[u] + bias[oc0 + u];
      float r1 = acc1[u] + bias[oc0 + u];
      r0 = r0 > 0.0f ? r0 : 0.1f * r0;
      r1 = r1 > 0.0f ? r1 : 0.1f * r1;
      *(float2*)(ob + (size_t)u * HWOUT) = make_float2(r0, r1);
    }
  } else {
#pragma unroll
    for (int u = 0; u < OCT; u++)
      *(float2*)(ob + (size_t)u * HWOUT) = make_float2(acc0[u], acc1[u]);
  }
}

// XCD-aware 1D wrappers: blockIdx.x % 8 == batch/slice index % 8, so each
// XCD's L2 holds only its own 1/8 of the input slices (g is the slow dim).
__global__ __launch_bounds__(256) void k_conv1(const float* __restrict__ i,
                                               const float* __restrict__ w,
                                               const float* __restrict__ b,
                                               float* __restrict__ o) {
  const int fb = blockIdx.x;  // 2720 = 8b * 85x * 4g
  const int bz = fb & 7;
  const int r = fb >> 3;
  conv_p2_body<3, 416, 416, 8, 1, 32>(i, w, b, o, r % 85, r / 85, bz);
}
__global__ __launch_bounds__(256) void k_conv2(const float* __restrict__ i,
                                               const float* __restrict__ w,
                                               const float* __restrict__ b,
                                               float* __restrict__ o) {
  const int fb = blockIdx.x;  // 1408 = 8b * 22x * 8g
  const int bz = fb & 7;
  const int r = fb >> 3;
  conv_p2_body<32, 208, 208, 8, 1, 64>(i, w, b, o, r % 22, r / 22, bz);
}
__global__ __launch_bounds__(256) void k_conv3(const float* __restrict__ i,
                                               const float* __restrict__ w,
                                               const float* __restrict__ b,
                                               float* __restrict__ o) {
  const int fb = blockIdx.x;  // 1536 = 8 * 6x * 2zhi * 16g
  const int low3 = fb & 7;
  int r = fb >> 3;
  const int x = r % 6;
  r /= 6;
  const int zhi = r & 1;
  const int g = r >> 1;
  conv_p2_body<64, 104, 104, 8, 2, 128>(i, w, b, o, x, g, low3 + 8 * zhi);
}

// ---------------------------------------------------------------------------
// conv4 (2048 blocks, XCD-swizzled) + grid-stride repack (1024 blocks).
// ---------------------------------------------------------------------------
__global__ __launch_bounds__(256) void k_conv4_repack(
    const float* __restrict__ x3, const float* __restrict__ w4,
    float* __restrict__ P, const float* __restrict__ w5,
    const float* __restrict__ wh2, const float* __restrict__ wh1,
    float* __restrict__ w5r, float* __restrict__ wh2r,
    float* __restrict__ wh1r) {
  const int fb = blockIdx.x;
  if (fb < 2048) {  // 8 * 2x * 4zhi * 32g
    const int low3 = fb & 7;
    int r = fb >> 3;
    const int x = r & 1;
    r >>= 1;
    const int zhi = r & 3;
    const int g = r >> 2;
    conv_p2_body<128, 52, 52, 8, 4, 256>(x3, w4, nullptr, P, x, g,
                                         low3 + 8 * zhi);
    return;
  }
  const int base = (fb - 2048) * 256 + threadIdx.x;
  for (int gid = base; gid < 1375488; gid += 1024 * 256) {
    if (gid < 1179648) {  // w5: COUT=512, CIN=256, CS=32, OCT=8
      const int oc = gid / (256 * 9), r = gid % (256 * 9);
      const int ci = r / 9, k = r % 9;
      const int g = oc / 8, u = oc % 8, s = ci / 32, cl = ci % 32;
      w5r[(((size_t)(g * 8 + s) * 32 + cl) * 8 + u) * 9 + k] = w5[gid];
    } else if (gid < 1179648 + 65280) {  // wh2: 255x256, SPLIT=2 -> CS=128
      const int t = gid - 1179648;
      const int oc = t / 256, ci = t % 256;
      const int g = oc / 17, u = oc % 17, s = ci / 128, cl = ci % 128;
      wh2r[((size_t)(g * 2 + s) * 128 + cl) * 17 + u] = wh2[t];
    } else {  // wh1: 255x512, SPLIT=16 -> CS=32
      const int t = gid - 1179648 - 65280;
      const int oc = t / 512, ci = t % 512;
      const int g = oc / 17, u = oc % 17, s = ci / 32, cl = ci % 32;
      wh1r[((size_t)(g * 16 + s) * 32 + cl) * 17 + u] = wh1[t];
    }
  }
}

// ---------------------------------------------------------------------------
// 1x1 head body (round-8 proven form), explicit block coords.
// ---------------------------------------------------------------------------
template <int CIN, int OCT, int SPLIT>
__device__ __forceinline__ void head_body(const float* __restrict__ in,
                                          const float* __restrict__ wgt,
                                          float* __restrict__ out, int HW,
                                          int bx, int g, int bz) {
  constexpr int CS = CIN / SPLIT;  // multiple of 8
  const int sp = bx * 256 + threadIdx.x;
  if (sp >= HW) return;
  const int oc0 = g * OCT;
  const int b = bz / SPLIT, s = bz % SPLIT;
  const float* ip = in + ((size_t)b * CIN + s * CS) * HW + sp;
  const float* wb = wgt + (size_t)(g * SPLIT + s) * CS * OCT;
  float acc[OCT];
#pragma unroll
  for (int u = 0; u < OCT; u++) acc[u] = 0.0f;

  auto fma4 = [&](const float v[4], int base) {
#pragma unroll
    for (int j = 0; j < 4; j++) {
#pragma unroll
      for (int u = 0; u < OCT; u++)
        acc[u] = fmaf(v[j], wb[(size_t)(base + j) * OCT + u], acc[u]);
    }
  };

  float vA[4], vB[4];
#pragma unroll
  for (int j = 0; j < 4; j++) {
    vA[j] = ip[(size_t)j * HW];
    vB[j] = ip[(size_t)(4 + j) * HW];
  }
  for (int c0 = 0; c0 < CS; c0 += 8) {
    float nA[4];
    if (c0 + 8 < CS) {
#pragma unroll
      for (int j = 0; j < 4; j++) nA[j] = ip[(size_t)(c0 + 8 + j) * HW];
    }
    fma4(vA, c0);
    float nB[4];
    if (c0 + 12 < CS) {
#pragma unroll
      for (int j = 0; j < 4; j++) nB[j] = ip[(size_t)(c0 + 12 + j) * HW];
    }
    fma4(vB, c0 + 4);
    if (c0 + 8 < CS) {
#pragma unroll
      for (int j = 0; j < 4; j++) vA[j] = nA[j];
    }
    if (c0 + 12 < CS) {
#pragma unroll
      for (int j = 0; j < 4; j++) vB[j] = nB[j];
    }
  }
#pragma unroll
  for (int u = 0; u < OCT; u++)
    out[((size_t)(s * 8 + b) * 255 + oc0 + u) * HW + sp] = acc[u];
}

// ---------------------------------------------------------------------------
// conv5 body (round-8 proven form), explicit g/z coords.
// ---------------------------------------------------------------------------
__device__ __forceinline__ void conv5_body(const float* __restrict__ in,
                                           const float* __restrict__ wgt,
                                           float* __restrict__ out, int g,
                                           int z) {
  constexpr int CIN = 256, HIN = 26, WIN = 26, OCT = 8, SPLIT = 8;
  constexpr int HWIN = 676, HWOUT = 169, WOUT = 13;
  constexpr int CS = CIN / SPLIT;  // 32
  const int b = z / SPLIT, s = z % SPLIT;
  const int oc0 = g * OCT;
  constexpr int COUT = 512;
  const int sp = threadIdx.x;
  if (sp >= HWOUT) return;
  const int oy = sp / WOUT, ox = sp % WOUT;
  const int iy0 = oy * 2, ix0 = ox * 2;
  const bool okY = (iy0 + 2 < HIN);
  const bool okX = (ix0 + 2 < WIN);
  const float* inb =
      in + ((size_t)b * CIN + s * CS) * HWIN + (size_t)iy0 * WIN + ix0;
  const float* wbase = wgt + (size_t)(g * SPLIT + s) * CS * OCT * 9;

  float acc[OCT];
#pragma unroll
  for (int u = 0; u < OCT; u++) acc[u] = 0.0f;

  auto load9 = [&](float v[9], const float* ip) {
#pragma unroll
    for (int ky = 0; ky < 3; ky++) {
      const bool rok = (ky < 2) || okY;
      const float* rp = ip + ky * WIN;
      float a0 = 0.f, a1 = 0.f, a2 = 0.f;
      if (rok) {
        const float2 p = *(const float2*)rp;  // 8B-aligned
        a0 = p.x;
        a1 = p.y;
        if (okX) a2 = rp[2];
      }
      v[ky * 3 + 0] = a0;
      v[ky * 3 + 1] = a1;
      v[ky * 3 + 2] = a2;
    }
  };
  auto fmablk = [&](const float v[9], int ci) {
#pragma unroll
    for (int u = 0; u < OCT; u++) {
#pragma unroll
      for (int k = 0; k < 9; k++)
        acc[u] = fmaf(v[k], wbase[(size_t)ci * OCT * 9 + u * 9 + k], acc[u]);
    }
  };

  float vA[9], vB[9];
  load9(vA, inb);
  load9(vB, inb + HWIN);
  for (int ci = 0; ci < CS; ci += 2) {
    float nA[9];
    if (ci + 2 < CS) load9(nA, inb + (size_t)(ci + 2) * HWIN);
    fmablk(vA, ci);
    float nB[9];
    if (ci + 3 < CS) load9(nB, inb + (size_t)(ci + 3) * HWIN);
    fmablk(vB, ci + 1);
    if (ci + 2 < CS) {
#pragma unroll
      for (int k = 0; k < 9; k++) vA[k] = nA[k];
    }
    if (ci + 3 < CS) {
#pragma unroll
      for (int k = 0; k < 9; k++) vB[k] = nB[k];
    }
  }

  float* ob = out + ((size_t)(s * 8 + b) * COUT + oc0) * HWOUT + sp;
#pragma unroll
  for (int u = 0; u < OCT; u++) ob[(size_t)u * HWOUT] = acc[u];
}

// ---------------------------------------------------------------------------
// Merged launch, XCD-swizzled: conv5 fb<4096 (fb%8 == z%8, g slowest);
// head2 blocks 4096..4815 (id%8 == z'%8).
// ---------------------------------------------------------------------------
__global__ __launch_bounds__(256) void k_h2c5(const float* __restrict__ x4,
                                              const float* __restrict__ w5r,
                                              const float* __restrict__ wh2r,
                                              float* __restrict__ P5,
                                              float* __restrict__ Ph2) {
  const int fb = blockIdx.x;
  if (fb < 4096) {  // 8 * 8zhi * 64g
    const int z = (fb & 7) + 8 * ((fb >> 3) & 7);
    const int g = fb >> 6;
    conv5_body(x4, w5r, P5, g, z);
  } else {
    const int id = fb - 4096;  // 720 = 8 * 3x * 2zhi * 15g
    const int low3 = id & 7;
    int r = id >> 3;
    const int x = r % 3;
    r /= 3;
    const int zhi = r & 1;
    const int g = r >> 1;
    head_body<256, 17, 2>(x4, wh2r, Ph2, 676, x, g, low3 + 8 * zhi);
  }
}

__global__ __launch_bounds__(256) void k_head1(const float* __restrict__ i,
                                               const float* __restrict__ w,
                                               float* __restrict__ o) {
  head_body<512, 17, 16>(i, w, o, 169, blockIdx.x, blockIdx.y, blockIdx.z);
}

// ---------------------------------------------------------------------------
// Reduce SPLIT partials (slice-major, deterministic) + bias (+ lrelu).
// ---------------------------------------------------------------------------
template <int SPLIT, bool LRELU>
__device__ __forceinline__ void reduce_body(const float* __restrict__ P,
                                            const float* __restrict__ bias,
                                            float* __restrict__ out, int COUT,
                                            int HWOUT, int N, int gid) {
  if (gid >= N) return;
  float a = 0.0f;
#pragma unroll
  for (int s = 0; s < SPLIT; s++) a += P[(size_t)s * N + gid];
  const int oc = (gid / HWOUT) % COUT;
  a += bias[oc];
  if (LRELU) a = a > 0.0f ? a : 0.1f * a;
  out[gid] = a;
}

template <int SPLIT, bool LRELU>
__global__ __launch_bounds__(256) void reduce_bias(
    const float* __restrict__ P, const float* __restrict__ bias,
    float* __restrict__ out, int COUT, int HWOUT, int N) {
  reduce_body<SPLIT, LRELU>(P, bias, out, COUT, HWOUT, N,
                            blockIdx.x * 256 + threadIdx.x);
}

// Merged reduce for conv5 (SPLIT=8, lrelu -> x5) + head2 (SPLIT=2 -> f2).
__global__ __launch_bounds__(256) void k_reduce_h2c5(
    const float* __restrict__ P5, const float* __restrict__ Ph2,
    const float* __restrict__ b5, const float* __restrict__ bh2,
    float* __restrict__ x5, float* __restrict__ f2) {
  const int fb = blockIdx.x;
  if (fb < 2704) {
    reduce_body<8, true>(P5, b5, x5, 512, 169, 692224,
                         fb * 256 + threadIdx.x);
  } else {
    reduce_body<2, false>(Ph2, bh2, f2, 255, 676, 1379040,
                          (fb - 2704) * 256 + threadIdx.x);
  }
}

// ---------------------------------------------------------------------------
// Decode both heads -> cand[b][i][8] = {y1,x1,y2,x2,obj,cc,label,score} and
// packed keys (score_bits<<32)|(0xFFFFFFFF-i) matching jax.lax.top_k order.
// ---------------------------------------------------------------------------
__global__ __launch_bounds__(256) void decode_kernel(
    const float* __restrict__ feat1, const float* __restrict__ feat2,
    float* __restrict__ cand, u64* __restrict__ keys) {
  const int gid = blockIdx.x * 256 + threadIdx.x;
  if (gid >= 8 * NCAND) return;
  const int b = gid / NCAND;
  const int i = gid % NCAND;
  const float* p;
  int rem, HW, W;
  float aw, ah;
  if (i < 507) {
    const int a = i / 169;
    rem = i % 169;
    HW = 169;
    W = 13;
    const float AW[3] = {81.f, 135.f, 344.f};
    const float AH[3] = {82.f, 169.f, 319.f};
    aw = AW[a];
    ah = AH[a];
    p = feat1 + ((size_t)b * 255 + a * 85) * 169 + rem;
  } else {
    const int j = i - 507;
    const int a = j / 676;
    rem = j % 676;
    HW = 676;
    W = 26;
    const float AW[3] = {10.f, 23.f, 37.f};
    const float AH[3] = {14.f, 27.f, 58.f};
    aw = AW[a];
    ah = AH[a];
    p = feat2 + ((size_t)b * 255 + a * 85) * 676 + rem;
  }
  const int gy = rem / W, gx = rem % W;
  const float invW = 1.0f / (float)W;
  float cx = (sig_(p[0]) + (float)gx) * invW;
  float cy = (sig_(p[(size_t)HW]) + (float)gy) * invW;
  float bw = expf(p[(size_t)2 * HW]) * aw / 416.0f;
  float bh = expf(p[(size_t)3 * HW]) * ah / 416.0f;
  float obj = sig_(p[(size_t)4 * HW]);
  float best = p[(size_t)5 * HW];
  int lab = 0;
  for (int c = 1; c < 80; ++c) {
    float v = p[(size_t)(5 + c) * HW];
    if (v > best) {
      best = v;
      lab = c;
    }
  }
  float cc = sig_(best);
  float score = obj * cc;
  if (score < 0.1f) score = 0.0f;
  float* o = cand + (size_t)gid * 8;
  o[0] = (cy - bh * 0.5f) * 416.0f;
  o[1] = (cx - bw * 0.5f) * 416.0f;
  o[2] = (cy + bh * 0.5f) * 416.0f;
  o[3] = (cx + bw * 0.5f) * 416.0f;
  o[4] = obj;
  o[5] = cc;
  o[6] = (float)lab;
  o[7] = score;
  keys[gid] = ((u64)__float_as_uint(score) << 32) |
              (u64)(0xFFFFFFFFu - (unsigned)i);
}

// ---------------------------------------------------------------------------
// Exact top-300 via rank (distinct keys -> bijection): sel[rank]=idx.
// ---------------------------------------------------------------------------
__global__ __launch_bounds__(256) void rank_select_kernel(
    const u64* __restrict__ keys, int* __restrict__ sel) {
  const int b = blockIdx.y;
  __shared__ u64 k[NCAND];
  const u64* kb = keys + (size_t)b * NCAND;
  for (int t = threadIdx.x; t < NCAND; t += 256) k[t] = kb[t];
  __syncthreads();
  const int idx = blockIdx.x * 256 + threadIdx.x;
  if (idx >= NCAND) return;
  const u64 me = k[idx];
  int rank = 0;
#pragma unroll 4
  for (int j = 0; j < NCAND; j++) rank += (k[j] > me) ? 1 : 0;
  if (rank < NKEEP) sel[b * NKEEP + rank] = idx;
}

// ---------------------------------------------------------------------------
// Per-image NMS (same semantics as reference fori_loop; see round-7 notes).
// ---------------------------------------------------------------------------
__global__ __launch_bounds__(256) void nms_kernel(
    const float* __restrict__ cand, const int* __restrict__ sel,
    float* __restrict__ out) {
  const int b = blockIdx.x;
  const int tid = threadIdx.x;
  const float* cb = cand + (size_t)b * NCAND * 8;

  __shared__ float4 bxv[NKEEP];
  __shared__ float2 oc2[NKEEP];
  __shared__ int lv[NKEEP];
  __shared__ u64 msk[NKEEP][6];
  __shared__ u64 validw[5];
  __shared__ u64 keepw[5];

  for (int t = tid; t < NKEEP; t += 256) {
    const int idx = sel[b * NKEEP + t];
    const float* c = cb + (size_t)idx * 8;
    const float4 c0 = *(const float4*)c;
    const float4 c1 = *(const float4*)(c + 4);
    bxv[t] = c0;
    oc2[t] = make_float2(c1.x, c1.y);
    lv[t] = (int)c1.z | ((c1.w > 0.0f) ? 0x10000 : 0);
  }
  __syncthreads();

  {
    const u64 m1 = __ballot((lv[tid] & 0x10000) != 0);
    if ((tid & 63) == 0) validw[tid >> 6] = m1;
    const u64 m2 = __ballot(tid < 44 && (lv[tid + 256] & 0x10000) != 0);
    if (tid == 0) validw[4] = m2;
  }

  for (int t = tid; t < NKEEP; t += 256) {
    u64 w[5] = {0, 0, 0, 0, 0};
    const int lvt = lv[t];
    if ((lvt & 0x10000) && t + 1 < NKEEP) {
      const float4 a = bxv[t];
      const float aarea = (a.z - a.x) * (a.w - a.y);
      int lv1 = lv[t + 1];
      float4 bb1 = bxv[t + 1];
      int j2 = (t + 2 < NKEEP) ? t + 2 : NKEEP - 1;
      int lv2 = (t + 2 < NKEEP) ? lv[j2] : -1;
      float4 bb2 = bxv[j2];
      for (int j = t + 1; j < NKEEP; ++j) {
        const int lvj = lv1;
        const float4 bbj = bb1;
        lv1 = lv2;
        bb1 = bb2;
        const int jn = (j + 2 < NKEEP) ? j + 2 : NKEEP - 1;
        lv2 = (j + 2 < NKEEP) ? lv[jn] : -1;
        bb2 = bxv[jn];
        if (lvj == lvt) {
          const float ty = fmaxf(a.x, bbj.x), tx = fmaxf(a.y, bbj.y);
          const float ey = fminf(a.z, bbj.z), ex = fminf(a.w, bbj.w);
          const float dy = fmaxf(ey - ty, 0.0f), dx = fmaxf(ex - tx, 0.0f);
          const float inter = dy * dx;
          const float barea = (bbj.z - bbj.x) * (bbj.w - bbj.y);
          const float iou = inter / (aarea + barea - inter + 1e-9f);
          if (iou > 0.5f) w[j >> 6] |= 1ull << (j & 63);
        }
      }
    }
#pragma unroll
    for (int q = 0; q < 5; q++) msk[t][q] = w[q];
  }
  __syncthreads();

  if (tid < 64) {
    const int L = tid;
    u64 slot[5][5];
#pragma unroll
    for (int q = 0; q < 5; q++) {
      const int row = q * 64 + L;
#pragma unroll
      for (int w = 0; w < 5; w++)
        slot[q][w] = (row < NKEEP) ? msk[row][w] : 0ull;
    }
    u64 kw[5];
#pragma unroll
    for (int w = 0; w < 5; w++) kw[w] = validw[w];
#pragma unroll
    for (int q = 0; q < 5; q++) {
      const int nb = (q == 4) ? (NKEEP - 256) : 64;
      for (int bit = 0; bit < nb; ++bit) {
        u64 r[5];
#pragma unroll
        for (int w = 0; w < 5; w++) r[w] = __shfl(slot[q][w], bit, 64);
        const u64 m = 0ull - ((kw[q] >> bit) & 1ull);
#pragma unroll
        for (int w = 0; w < 5; w++) kw[w] &= ~(r[w] & m);
      }
    }
    if (L == 0) {
#pragma unroll
      for (int w = 0; w < 5; w++) keepw[w] = kw[w];
    }
  }
  __syncthreads();

  float* ob = out + (size_t)b * NKEEP * 7;
  for (int t = tid; t < NKEEP; t += 256) {
    const bool k = (keepw[t >> 6] >> (t & 63)) & 1ull;
    float* r = ob + (size_t)t * 7;
    if (k) {
      const float4 a = bxv[t];
      const float2 o2 = oc2[t];
      r[0] = a.x;
      r[1] = a.y;
      r[2] = a.z;
      r[3] = a.w;
      r[4] = o2.x;
      r[5] = o2.y;
      r[6] = (float)(lv[t] & 0xFFFF);
    } else {
      r[0] = 0.0f; r[1] = 0.0f; r[2] = 0.0f; r[3] = 0.0f;
      r[4] = 0.0f; r[5] = 0.0f; r[6] = 0.0f;
    }
  }
}

// ---------------------------------------------------------------------------
// Workspace (float offsets), lifetime-checked (identical to round 12):
//   x1  : [0, 11075584)          x2/P5: [11075584, 16613376)
//   P3  : [5537792, 11075584)    x3 : [0, 2768896)
//   x4  : [2768896, 4153344)     f2 : [4153344, 5532384)
//   x5  : [5532384, 6224608)     f1 : [6224608, 6569368)
//   w5r : [6224608, 7404256)     wh2r: [7404256, 7469536)
//   wh1r: [7469536, 7600096)     Ph2 : [7600096, 10358176)
//   cd  : [6569368, 6731608)  keys: [6731608, 6772168)  sel: [6772168, 6774568)
// Peak = 16613376 floats = 66.5 MB.
// ---------------------------------------------------------------------------
extern "C" void kernel_launch(void* const* d_in, const int* in_sizes, int n_in,
                              void* d_out, int out_size, void* d_ws,
                              size_t ws_size, hipStream_t stream) {
  const float* images = (const float*)d_in[0];
  const float* w1 = (const float*)d_in[1];
  const float* b1 = (const float*)d_in[2];
  const float* w2 = (const float*)d_in[3];
  const float* b2 = (const float*)d_in[4];
  const float* w3 = (const float*)d_in[5];
  const float* b3 = (const float*)d_in[6];
  const float* w4 = (const float*)d_in[7];
  const float* b4 = (const float*)d_in[8];
  const float* w5 = (const float*)d_in[9];
  const float* b5 = (const float*)d_in[10];
  const float* wh1 = (const float*)d_in[11];
  const float* bh1 = (const float*)d_in[12];
  const float* wh2 = (const float*)d_in[13];
  const float* bh2 = (const float*)d_in[14];
  float* ws = (float*)d_ws;

  float* x1 = ws + 0;
  float* x2 = ws + 11075584;
  float* P3 = ws + 5537792;
  float* x3 = ws + 0;
  float* x4 = ws + 2768896;
  float* f2 = ws + 4153344;
  float* x5 = ws + 5532384;
  float* f1 = ws + 6224608;
  float* cd = ws + 6569368;
  u64* keys = (u64*)(ws + 6731608);
  int* sel = (int*)(ws + 6772168);
  float* P = ws + 11075584;
  float* w5r = ws + 6224608;
  float* wh2r = ws + 7404256;
  float* wh1r = ws + 7469536;
  float* Ph2 = ws + 7600096;

  // conv1: 2720 blocks, XCD-swizzled
  k_conv1<<<2720, 256, 0, stream>>>(images, w1, b1, x1);
  // conv2: 1408 blocks, XCD-swizzled
  k_conv2<<<1408, 256, 0, stream>>>(x1, w2, b2, x2);
  // conv3: split-K x2 -> 1536 blocks, XCD-swizzled
  k_conv3<<<1536, 256, 0, stream>>>(x2, w3, nullptr, P3);
  reduce_bias<2, true><<<(2768896 + 255) / 256, 256, 0, stream>>>(P3, b3, x3, 128, 2704, 2768896);
  // conv4 (2048, XCD-swizzled) + repack (1024)
  k_conv4_repack<<<3072, 256, 0, stream>>>(x3, w4, P, w5, wh2, wh1, w5r, wh2r, wh1r);
  reduce_bias<4, true><<<(1384448 + 255) / 256, 256, 0, stream>>>(P, b4, x4, 256, 676, 1384448);
  // conv5 (4096) + head2 SPLIT=2 (720), both XCD-swizzled
  k_h2c5<<<4816, 256, 0, stream>>>(x4, w5r, wh2r, P, Ph2);
  k_reduce_h2c5<<<2704 + 5388, 256, 0, stream>>>(P, Ph2, b5, bh2, x5, f2);
  // head1: split-K x16 -> 1920 blocks
  k_head1<<<dim3(1, 15, 128), 256, 0, stream>>>(x5, wh1r, P);
  reduce_bias<16, false><<<(344760 + 255) / 256, 256, 0, stream>>>(P, bh1, f1, 255, 169, 344760);

  decode_kernel<<<80, 256, 0, stream>>>(f1, f2, cd, keys);
  rank_select_kernel<<<dim3(10, 8), 256, 0, stream>>>(keys, sel);
  nms_kernel<<<8, 256, 0, stream>>>(cd, sel, (float*)d_out);
}